// Round 9
// baseline (428.957 us; speedup 1.0000x reference)
//
#include <hip/hip_runtime.h>
#include <hip/hip_bf16.h>
#include <math.h>

// Model dims
#define SEQ 2048
// B=2, DM=512, DI=1024, N=16, K=4, R=32, H=8, V=10000

typedef __attribute__((ext_vector_type(4))) float f32x4;
typedef __attribute__((ext_vector_type(8))) short bf16x8s;
typedef __attribute__((ext_vector_type(4))) short short4v;
typedef __attribute__((ext_vector_type(8))) unsigned short ushort8;
typedef __attribute__((ext_vector_type(2))) unsigned int uint2v;

__device__ __forceinline__ short f2bf(float f) {
  union { float f; unsigned u; } c; c.f = f;
  unsigned u = c.u;
  u += 0x7fffu + ((u >> 16) & 1u);   // RNE
  return (short)(u >> 16);
}
__device__ __forceinline__ float bf2f(unsigned short u) {
  union { unsigned u; float f; } c; c.u = ((unsigned)u) << 16; return c.f;
}

__device__ __forceinline__ void lds_load16(const void* g, void* s) {
  __builtin_amdgcn_global_load_lds(
      (const __attribute__((address_space(1))) void*)g,
      (__attribute__((address_space(3))) void*)s, 16, 0, 0);
}

// =================== bf16 MFMA GEMM: C[M,N] = A[M,K] @ B[N,K]^T ===================
// A,B bf16 (K%64==0, lda/ldb %8==0, M%512==0, N%4==0). nbm = M/128 must be %4.
// EPI: 0 none, 1 +bias. OUTBF: 1 -> bf16 C, 0 -> f32 C.
// blockIdx.y==1 selects the A1/B1/C1 tensor set (dual-direction launches).
// Pipeline (T3+T4): STAGE(t+1) issued first, then counted s_waitcnt vmcnt(8),
// barrier, ds_read+MFMA, barrier. XOR-chunk swizzled LDS; LDS-staged epilogue.
// Block order: bijective XCD chunks + 4-bm supertiles (bm-inner, bn-outer).
template<int EPI, int OUTBF>
__launch_bounds__(256)
__global__ void gemm_bf16(const unsigned short* A, const unsigned short* B,
                          void* Cv, const float* __restrict__ bias,
                          int M, int N, int K, int lda, int ldb, int ldc, int nbn,
                          const unsigned short* A1, const unsigned short* B1, void* C1) {
  __shared__ char smem[67584];   // 2x(16KB A + 16KB B) dbuf; 128x132 f32 epilogue tile

  if (blockIdx.y) { A = A1; B = B1; Cv = C1; }

  // bijective XCD chunk swizzle (m204)
  const int nwg = gridDim.x;
  const int g = blockIdx.x;
  const int q = nwg >> 3, r = nwg & 7;
  const int xcd = g & 7, cidx = g >> 3;
  const int wg = (xcd < r ? xcd * (q + 1) : r * (q + 1) + (xcd - r) * q) + cidx;
  // 4-bm supertile order: bm fastest within group of 4, then bn, then bm-group
  const int sup = nbn << 2;
  const int bmg = wg / sup, rem = wg % sup;
  const int bn = rem >> 2;
  const int bm = (bmg << 2) + (rem & 3);
  const int m0 = bm * 128, n0 = bn * 128;

  const int tid = threadIdx.x, lane = tid & 63, wave = tid >> 6;
  const int wr = (wave >> 1) * 64, wc = (wave & 1) * 64;
  const int fr = lane & 15, fq = lane >> 4;
  const int srow = tid >> 3;   // 0..31
  const int scc  = tid & 7;    // column chunk 0..7 (8 bf16 each)

  f32x4 acc[4][4] = {};
  const int nkt = K >> 6;

  auto STAGE = [&](int buf, int kt) {
    const int k0 = kt << 6;
    unsigned short* sAb = (unsigned short*)(smem + buf * 32768);
    unsigned short* sBb = (unsigned short*)(smem + buf * 32768 + 16384);
    #pragma unroll
    for (int j = 0; j < 4; j++) {
      int lrow = j * 32 + srow;
      int gcol = (scc ^ (lrow & 7)) * 8;
      lds_load16(A + (size_t)(m0 + lrow) * lda + k0 + gcol, &sAb[(j * 256 + wave * 64) * 8]);
    }
    #pragma unroll
    for (int j = 0; j < 4; j++) {
      int lrow = j * 32 + srow;
      int gcol = (scc ^ (lrow & 7)) * 8;
      int grow = n0 + lrow; if (grow >= N) grow = N - 1;   // clamp; junk never stored
      lds_load16(B + (size_t)grow * ldb + k0 + gcol, &sBb[(j * 256 + wave * 64) * 8]);
    }
  };

  STAGE(0, 0);

  int cur = 0;
  for (int kt = 0; kt < nkt; kt++) {
    if (kt + 1 < nkt) {
      STAGE(cur ^ 1, kt + 1);                           // 8 new loads in flight
      asm volatile("s_waitcnt vmcnt(8)" ::: "memory");  // previous stage landed (wave-local)
    } else {
      asm volatile("s_waitcnt vmcnt(0)" ::: "memory");  // last tile: full drain
    }
    __builtin_amdgcn_s_barrier();                       // all waves' stage landed
    __builtin_amdgcn_sched_barrier(0);
    const unsigned short* As = (const unsigned short*)(smem + cur * 32768);
    const unsigned short* Bs = (const unsigned short*)(smem + cur * 32768 + 16384);
    #pragma unroll
    for (int ks = 0; ks < 2; ks++) {
      bf16x8s af[4], bfv[4];
      #pragma unroll
      for (int i = 0; i < 4; i++) {
        int ra = wr + i * 16 + fr;
        af[i] = *(const bf16x8s*)&As[ra * 64 + (((ks << 2) + fq) ^ (ra & 7)) * 8];
      }
      #pragma unroll
      for (int i = 0; i < 4; i++) {
        int rb = wc + i * 16 + fr;
        bfv[i] = *(const bf16x8s*)&Bs[rb * 64 + (((ks << 2) + fq) ^ (rb & 7)) * 8];
      }
      #pragma unroll
      for (int i = 0; i < 4; i++)
        #pragma unroll
        for (int j = 0; j < 4; j++)
          acc[i][j] = __builtin_amdgcn_mfma_f32_16x16x32_bf16(af[i], bfv[j], acc[i][j], 0, 0, 0);
    }
    __builtin_amdgcn_s_barrier();   // all reads of cur done -> next STAGE may overwrite it
    cur ^= 1;
  }

  // ---- epilogue: stage f32 tile in LDS, write coalesced ----
  float* ct = (float*)smem;   // [128][132]
  #pragma unroll
  for (int i = 0; i < 4; i++)
    #pragma unroll
    for (int j = 0; j < 4; j++)
      #pragma unroll
      for (int r4 = 0; r4 < 4; r4++)
        ct[(wr + i * 16 + fq * 4 + r4) * 132 + wc + j * 16 + fr] = acc[i][j][r4];
  __syncthreads();
  const int half = lane >> 5;
  const int col4 = (lane & 31) * 4;
  const int cn = n0 + col4;
  #pragma unroll
  for (int it = 0; it < 16; it++) {
    int row = wave * 32 + it * 2 + half;
    f32x4 v = *(const f32x4*)&ct[row * 132 + col4];
    if (cn < N) {
      if (EPI >= 1) {
        f32x4 b4 = *(const f32x4*)&bias[cn];
        #pragma unroll
        for (int j = 0; j < 4; j++) v[j] += b4[j];
      }
      if (OUTBF) {
        unsigned short h0 = (unsigned short)f2bf(v[0]), h1 = (unsigned short)f2bf(v[1]);
        unsigned short h2 = (unsigned short)f2bf(v[2]), h3 = (unsigned short)f2bf(v[3]);
        uint2v o = { (unsigned)h0 | ((unsigned)h1 << 16), (unsigned)h2 | ((unsigned)h3 << 16) };
        *(uint2v*)((unsigned short*)Cv + (size_t)(m0 + row) * ldc + cn) = o;
      } else {
        float* dst = (float*)Cv + (size_t)(m0 + row) * ldc + cn;
        if (EPI == 1) __builtin_nontemporal_store(v, (f32x4*)dst);  // final logits: stream past L2
        else          *(f32x4*)dst = v;
      }
    }
  }
}

// =================== f32-input GEMM (mel K=80; dt K=32 with softplus) ===================
// EPI: 1 +bias, 2 +bias+softplus. blockIdx.z==1 selects A1/B1/C1/bias1.
#define LDT 40
template<int EPI, int OUTBF>
__launch_bounds__(256)
__global__ void gemm_f32in(const float* A, const float* B,
                           void* Cv, const float* bias,
                           int M, int N, int K, int lda, int ldb, int ldc,
                           const float* A1, const float* B1, void* C1, const float* bias1) {
  __shared__ short As[128 * LDT];
  __shared__ short Bs[128 * LDT];
  if (blockIdx.z) { A = A1; B = B1; Cv = C1; bias = bias1; }
  const int tid  = threadIdx.x;
  const int lane = tid & 63;
  const int wave = tid >> 6;
  const int m0 = blockIdx.y * 128;
  const int n0 = blockIdx.x * 128;
  const int wr = (wave >> 1) * 64;
  const int wc = (wave & 1) * 64;
  const int srow = tid >> 3;
  const int scol = (tid & 7) * 4;
  const int fr = lane & 15;
  const int fq = lane >> 4;

  f32x4 acc[4][4] = {};

  for (int k0 = 0; k0 < K; k0 += 32) {
    const bool kok = (k0 + scol) < K;
    #pragma unroll
    for (int rr = 0; rr < 128; rr += 32) {
      int r = srow + rr;
      f32x4 v = {0.f, 0.f, 0.f, 0.f};
      if (kok) v = *(const f32x4*)(A + (size_t)(m0 + r) * lda + k0 + scol);
      short4v s = { f2bf(v[0]), f2bf(v[1]), f2bf(v[2]), f2bf(v[3]) };
      *(short4v*)(&As[r * LDT + scol]) = s;
    }
    #pragma unroll
    for (int rr = 0; rr < 128; rr += 32) {
      int r = srow + rr;
      f32x4 v = {0.f, 0.f, 0.f, 0.f};
      if (kok && (n0 + r) < N) v = *(const f32x4*)(B + (size_t)(n0 + r) * ldb + k0 + scol);
      short4v s = { f2bf(v[0]), f2bf(v[1]), f2bf(v[2]), f2bf(v[3]) };
      *(short4v*)(&Bs[r * LDT + scol]) = s;
    }
    __syncthreads();
    bf16x8s af[4], bfv[4];
    #pragma unroll
    for (int i = 0; i < 4; i++)
      af[i]  = *(const bf16x8s*)(&As[(wr + i * 16 + fr) * LDT + fq * 8]);
    #pragma unroll
    for (int i = 0; i < 4; i++)
      bfv[i] = *(const bf16x8s*)(&Bs[(wc + i * 16 + fr) * LDT + fq * 8]);
    #pragma unroll
    for (int i = 0; i < 4; i++)
      #pragma unroll
      for (int j = 0; j < 4; j++)
        acc[i][j] = __builtin_amdgcn_mfma_f32_16x16x32_bf16(af[i], bfv[j], acc[i][j], 0, 0, 0);
    __syncthreads();
  }

  #pragma unroll
  for (int j = 0; j < 4; j++) {
    int cn = n0 + wc + j * 16 + fr;
    if (cn < N) {
      float bv = 0.f;
      if (EPI >= 1) bv = bias[cn];
      #pragma unroll
      for (int i = 0; i < 4; i++) {
        #pragma unroll
        for (int r4 = 0; r4 < 4; r4++) {
          int cm = m0 + wr + i * 16 + fq * 4 + r4;
          float val = acc[i][j][r4] + bv;
          if (EPI == 2) val = fmaxf(val, 0.f) + log1pf(__expf(-fabsf(val)));
          if (OUTBF) ((unsigned short*)Cv)[(size_t)cm * ldc + cn] = (unsigned short)f2bf(val);
          else       ((float*)Cv)[(size_t)cm * ldc + cn] = val;
        }
      }
    }
  }
}

// =================== weight f32 -> bf16 conversion (12 tensors, one launch) ===================
struct CvtArgs { const float* s[12]; unsigned short* d[12]; int n[12]; };
__global__ void cvt_many(CvtArgs a) {
  int y = blockIdx.y;
  int i = (blockIdx.x * 256 + threadIdx.x) * 8;
  if (i >= a.n[y]) return;
  const float* s = a.s[y];
  f32x4 v0 = *(const f32x4*)(s + i);
  f32x4 v1 = *(const f32x4*)(s + i + 4);
  ushort8 o = { (unsigned short)f2bf(v0[0]), (unsigned short)f2bf(v0[1]),
                (unsigned short)f2bf(v0[2]), (unsigned short)f2bf(v0[3]),
                (unsigned short)f2bf(v1[0]), (unsigned short)f2bf(v1[1]),
                (unsigned short)f2bf(v1[2]), (unsigned short)f2bf(v1[3]) };
  *(ushort8*)(a.d[y] + i) = o;
}

// =================== tiny attention (L=2) over bf16 qkv ===================
__global__ void attn_kernel(const unsigned short* __restrict__ qkv, unsigned short* __restrict__ o) {
  int gw = blockIdx.x * 4 + (threadIdx.x >> 6);
  int lane = threadIdx.x & 63;
  int n = gw >> 3, h = gw & 7;
  size_t r0 = (size_t)n * 1536 + h * 64 + lane;
  size_t r1 = (size_t)(SEQ + n) * 1536 + h * 64 + lane;
  float q0 = bf2f(qkv[r0]), k0 = bf2f(qkv[r0 + 512]), v0 = bf2f(qkv[r0 + 1024]);
  float q1 = bf2f(qkv[r1]), k1 = bf2f(qkv[r1 + 512]), v1 = bf2f(qkv[r1 + 1024]);
  float s00 = q0 * k0, s01 = q0 * k1, s10 = q1 * k0, s11 = q1 * k1;
  #pragma unroll
  for (int off = 32; off > 0; off >>= 1) {
    s00 += __shfl_xor(s00, off);
    s01 += __shfl_xor(s01, off);
    s10 += __shfl_xor(s10, off);
    s11 += __shfl_xor(s11, off);
  }
  const float sc = 0.125f;
  s00 *= sc; s01 *= sc; s10 *= sc; s11 *= sc;
  float mx0 = fmaxf(s00, s01), mx1 = fmaxf(s10, s11);
  float e00 = __expf(s00 - mx0), e01 = __expf(s01 - mx0);
  float e10 = __expf(s10 - mx1), e11 = __expf(s11 - mx1);
  float i0 = 1.f / (e00 + e01), i1 = 1.f / (e10 + e11);
  size_t w0 = (size_t)n * 512 + h * 64 + lane;
  size_t w1 = (size_t)(SEQ + n) * 512 + h * 64 + lane;
  o[w0] = (unsigned short)f2bf((e00 * v0 + e01 * v1) * i0);
  o[w1] = (unsigned short)f2bf((e10 * v0 + e11 * v1) * i1);
}

// =================== LN(a+b) over 512, bf16 in/out; DUAL: also write time-flipped copy ===================
template<int DUAL>
__global__ void ln_res_kernel(const unsigned short* __restrict__ a, const unsigned short* __restrict__ b,
                              const float* __restrict__ g, const float* __restrict__ be,
                              unsigned short* __restrict__ out, unsigned short* __restrict__ out2) {
  int row = blockIdx.x * 4 + (threadIdx.x >> 6);
  int lane = threadIdx.x & 63;
  ushort8 va = *(const ushort8*)(a + (size_t)row * 512 + lane * 8);
  ushort8 vb = *(const ushort8*)(b + (size_t)row * 512 + lane * 8);
  float v[8];
  #pragma unroll
  for (int j = 0; j < 8; j++) v[j] = bf2f(va[j]) + bf2f(vb[j]);
  float s = 0.f, s2 = 0.f;
  #pragma unroll
  for (int j = 0; j < 8; j++) { s += v[j]; s2 += v[j] * v[j]; }
  #pragma unroll
  for (int off = 32; off > 0; off >>= 1) { s += __shfl_xor(s, off); s2 += __shfl_xor(s2, off); }
  float mu = s * (1.f / 512.f);
  float var = s2 * (1.f / 512.f) - mu * mu;
  float rs = rsqrtf(var + 1e-5f);
  const float* pg = g + lane * 8;
  const float* pe = be + lane * 8;
  ushort8 o;
  #pragma unroll
  for (int j = 0; j < 8; j++) o[j] = (unsigned short)f2bf((v[j] - mu) * rs * pg[j] + pe[j]);
  *(ushort8*)(out + (size_t)row * 512 + lane * 8) = o;
  if (DUAL) {
    int t = row & (SEQ - 1), bb = row >> 11;
    int frow = (bb << 11) | (SEQ - 1 - t);
    *(ushort8*)(out2 + (size_t)frow * 512 + lane * 8) = o;
  }
}

// =================== depthwise causal conv(K=4)+silu, dual-direction ===================
struct ConvArgs {
  const unsigned short* xz[2];
  const float* w[2];
  const float* cb[2];
  unsigned short* xc[2];
};
__global__ void conv_silu_kernel(ConvArgs a) {
  int dir = blockIdx.y;
  int idx = blockIdx.x * 256 + threadIdx.x;     // over B*S*(DI/8) = 524288
  int dc = (idx & 127) * 8;
  int t  = (idx >> 7) & (SEQ - 1);
  int b  = idx >> 18;
  const float* w = a.w[dir];
  f32x4 wv[8];
  #pragma unroll
  for (int j = 0; j < 8; j++) wv[j] = *(const f32x4*)(w + (dc + j) * 4);
  float acc[8];
  f32x4 cb0 = *(const f32x4*)(a.cb[dir] + dc), cb1 = *(const f32x4*)(a.cb[dir] + dc + 4);
  #pragma unroll
  for (int j = 0; j < 4; j++) { acc[j] = cb0[j]; acc[4 + j] = cb1[j]; }
  const unsigned short* base = a.xz[dir] + ((size_t)b * SEQ) * 2048 + dc;
  #pragma unroll
  for (int k = 0; k < 4; k++) {
    int tt = t - 3 + k;
    if (tt >= 0) {
      ushort8 xv = *(const ushort8*)(base + (size_t)tt * 2048);
      #pragma unroll
      for (int j = 0; j < 8; j++) acc[j] += wv[j][k] * bf2f(xv[j]);
    }
  }
  ushort8 o;
  #pragma unroll
  for (int j = 0; j < 8; j++) {
    float v = acc[j];
    o[j] = (unsigned short)f2bf(v / (1.f + __expf(-v)));
  }
  *(ushort8*)(a.xc[dir] + (size_t)idx * 8) = o;
}

// =================== chunked selective scan, dual-direction (dt from GEMM, gate+flip fused) ===================
#define CL 32
#define NC 64

struct ScanArgs {
  const unsigned short* xc[2];
  const float* dbl[2];
  const float* A_log[2];
  const float* dt[2];       // precomputed softplus(dt) f32, (B*S, DI)
  const float* Dp[2];
  const unsigned short* xz[2];
  float* hend[2];
  float* apr[2];
  float* h0[2];
  unsigned short* ys[2];
};

__global__ void scan_p1(ScanArgs s) {
  int dir = blockIdx.y;
  int tid = blockIdx.x * 256 + threadIdx.x;   // B*NC*DI = 131072
  int d = tid & 1023;
  int c = (tid >> 10) & (NC - 1);
  int b = tid >> 16;
  float A[16];
  #pragma unroll
  for (int q = 0; q < 4; q++) {
    f32x4 v = *(const f32x4*)(s.A_log[dir] + d * 16 + q * 4);
    #pragma unroll
    for (int j = 0; j < 4; j++) A[q * 4 + j] = -__expf(v[j]);
  }
  float h[16] = {};
  float ap[16];
  #pragma unroll
  for (int n = 0; n < 16; n++) ap[n] = 1.f;
  const unsigned short* xcp = s.xc[dir] + ((size_t)b * SEQ) * 1024 + d;
  const float* dtp = s.dt[dir] + ((size_t)b * SEQ) * 1024 + d;
  const float* dbp = s.dbl[dir] + ((size_t)b * SEQ) * 64;
  const int t0 = c * CL;
  for (int t = t0; t < t0 + CL; t++) {
    const float* dr = dbp + (size_t)t * 64;
    float dtv = dtp[(size_t)t * 1024];
    float dx = dtv * bf2f(xcp[(size_t)t * 1024]);
    float Bv[16];
    #pragma unroll
    for (int q = 0; q < 4; q++) {
      f32x4 v = *(const f32x4*)(dr + 32 + q * 4);
      #pragma unroll
      for (int j = 0; j < 4; j++) Bv[q * 4 + j] = v[j];
    }
    #pragma unroll
    for (int n = 0; n < 16; n++) {
      float e = __expf(dtv * A[n]);
      h[n] = e * h[n] + dx * Bv[n];
      ap[n] *= e;
    }
  }
  size_t o = ((size_t)((b * NC + c) * 1024 + d)) * 16;
  #pragma unroll
  for (int q = 0; q < 4; q++) {
    f32x4 vh = { h[q * 4], h[q * 4 + 1], h[q * 4 + 2], h[q * 4 + 3] };
    f32x4 va = { ap[q * 4], ap[q * 4 + 1], ap[q * 4 + 2], ap[q * 4 + 3] };
    *(f32x4*)(s.hend[dir] + o + q * 4) = vh;
    *(f32x4*)(s.apr[dir] + o + q * 4) = va;
  }
}

__global__ void scan_p2(ScanArgs s) {
  int dir = blockIdx.y;
  int tid = blockIdx.x * 256 + threadIdx.x;   // B*DI*N = 32768
  int n = tid & 15;
  int d = (tid >> 4) & 1023;
  int b = tid >> 14;
  const float* hend = s.hend[dir];
  const float* apr  = s.apr[dir];
  float* h0 = s.h0[dir];
  float h = 0.f;
  for (int c = 0; c < NC; c++) {
    size_t idx = ((size_t)((b * NC + c) * 1024 + d)) * 16 + n;
    h0[idx] = h;
    h = apr[idx] * h + hend[idx];
  }
}

// p3: recompute with h0, emit gated output, write (dir-1 time-flipped)
__global__ void scan_p3(ScanArgs s) {
  int dir = blockIdx.y;
  int tid = blockIdx.x * 256 + threadIdx.x;   // B*NC*DI = 131072
  int d = tid & 1023;
  int c = (tid >> 10) & (NC - 1);
  int b = tid >> 16;
  float A[16];
  #pragma unroll
  for (int q = 0; q < 4; q++) {
    f32x4 v = *(const f32x4*)(s.A_log[dir] + d * 16 + q * 4);
    #pragma unroll
    for (int j = 0; j < 4; j++) A[q * 4 + j] = -__expf(v[j]);
  }
  const float Dv = s.Dp[dir][d];
  float h[16];
  size_t o = ((size_t)((b * NC + c) * 1024 + d)) * 16;
  #pragma unroll
  for (int q = 0; q < 4; q++) {
    f32x4 v = *(const f32x4*)(s.h0[dir] + o + q * 4);
    #pragma unroll
    for (int j = 0; j < 4; j++) h[q * 4 + j] = v[j];
  }
  const unsigned short* xcp = s.xc[dir] + ((size_t)b * SEQ) * 1024 + d;
  const float* dtp = s.dt[dir] + ((size_t)b * SEQ) * 1024 + d;
  const unsigned short* zp  = s.xz[dir] + ((size_t)b * SEQ) * 2048 + 1024 + d;
  const float* dbp = s.dbl[dir] + ((size_t)b * SEQ) * 64;
  unsigned short* ysp = s.ys[dir] + ((size_t)b * SEQ) * 1024 + d;
  const int t0 = c * CL;
  for (int t = t0; t < t0 + CL; t++) {
    const float* dr = dbp + (size_t)t * 64;
    float dtv = dtp[(size_t)t * 1024];
    float xcv = bf2f(xcp[(size_t)t * 1024]);
    float dx = dtv * xcv;
    float Bv[16], Cv[16];
    #pragma unroll
    for (int q = 0; q < 4; q++) {
      f32x4 v = *(const f32x4*)(dr + 32 + q * 4);
      f32x4 w = *(const f32x4*)(dr + 48 + q * 4);
      #pragma unroll
      for (int j = 0; j < 4; j++) { Bv[q * 4 + j] = v[j]; Cv[q * 4 + j] = w[j]; }
    }
    float y = 0.f;
    #pragma unroll
    for (int n = 0; n < 16; n++) {
      float e = __expf(dtv * A[n]);
      h[n] = e * h[n] + dx * Bv[n];
      y += h[n] * Cv[n];
    }
    // gate: (y + xc*D) * silu(z)
    float z = bf2f(zp[(size_t)t * 2048]);
    float out = (y + xcv * Dv) * (z / (1.f + __expf(-z)));
    int tw = dir ? (SEQ - 1 - t) : t;
    ysp[(size_t)tw * 1024] = (unsigned short)f2bf(out);
  }
}

extern "C" void kernel_launch(void* const* d_in, const int* in_sizes, int n_in,
                              void* d_out, int out_size, void* d_ws, size_t ws_size,
                              hipStream_t stream) {
  (void)in_sizes; (void)n_in; (void)out_size; (void)ws_size;
  const float* mel        = (const float*)d_in[0];
  const float* mel_w      = (const float*)d_in[1];
  const float* mel_b      = (const float*)d_in[2];
  const float* attn_in_b  = (const float*)d_in[4];
  const float* attn_out_b = (const float*)d_in[6];
  const float* ln1_g = (const float*)d_in[7];
  const float* ln1_b = (const float*)d_in[8];
  const float* ln2_g = (const float*)d_in[9];
  const float* ln2_b = (const float*)d_in[10];
  const float* bim_b = (const float*)d_in[30];
  const float* out_b = (const float*)d_in[32];

  char* wsb = (char*)d_ws;
  char* obb = (char*)d_out;

  // ---- bf16 weights in ws (byte offsets) ----
  unsigned short* w_attn_in  = (unsigned short*)(wsb + 0);          // 786432
  unsigned short* w_attn_out = (unsigned short*)(wsb + 1572864);    // 262144
  unsigned short* w_dir[2][4];
  for (int dir = 0; dir < 2; dir++) {
    size_t base = 2097152 + (size_t)dir * 3342336;
    w_dir[dir][0] = (unsigned short*)(wsb + base);                  // in_w
    w_dir[dir][1] = (unsigned short*)(wsb + base + 2097152);        // x_w
    w_dir[dir][2] = (unsigned short*)(wsb + base + 2228224);        // (spare)
    w_dir[dir][3] = (unsigned short*)(wsb + base + 2293760);        // out_w
  }
  unsigned short* w_bim = (unsigned short*)(wsb + 8781824);         // 524288
  unsigned short* w_out = (unsigned short*)(wsb + 9830400);         // 5120000

  // ---- bf16 activations in ws ----
  unsigned short* x0     = (unsigned short*)(wsb + 20971520);
  unsigned short* x1     = (unsigned short*)(wsb + 25165824);
  unsigned short* x1f    = (unsigned short*)(wsb + 29360128);
  unsigned short* attn_o = (unsigned short*)(wsb + 33554432);
  unsigned short* xc0    = (unsigned short*)(wsb + 37748736);  // 8.39MB
  unsigned short* ysb0   = (unsigned short*)(wsb + 46137344);  // 8.39MB
  unsigned short* mout   = (unsigned short*)(wsb + 62914560);  // 8.39MB
  unsigned short* minter = (unsigned short*)(wsb + 71303168);
  unsigned short* x2     = (unsigned short*)(wsb + 75497472);
  float*          dbl0   = (float*)(wsb + 79691776);           // 1.05MB

  // ---- d_out scratch (dead until final GEMM overwrites all; 163.84MB) ----
  unsigned short* qkv  = (unsigned short*)(obb + 0);           // 12.58MB
  unsigned short* xz0  = (unsigned short*)(obb + 12582912);    // 16.78MB
  unsigned short* xz1  = (unsigned short*)(obb + 29360128);    // 16.78MB
  unsigned short* xc1  = (unsigned short*)(obb + 46137344);    // 8.39MB
  unsigned short* ysb1 = (unsigned short*)(obb + 54525952);    // 8.39MB
  float* hend0 = (float*)(obb + 62914560);                     // 8.39MB
  float* hend1 = (float*)(obb + 71303168);
  float* apr0  = (float*)(obb + 79691776);
  float* apr1  = (float*)(obb + 88080384);
  float* h0s0  = (float*)(obb + 96468992);
  float* h0s1  = (float*)(obb + 104857600);
  float* dbl1  = (float*)(obb + 113246208);                    // 1.05MB
  float* dtf0  = (float*)(obb + 114294784);                    // 16.78MB
  float* dtf1  = (float*)(obb + 131072000);                    // 16.78MB -> ends 147.85MB
  float* ob    = (float*)d_out;

  dim3 blk(256);

  // 0. convert weights to bf16
  {
    CvtArgs a;
    const float* srcs[12] = { (const float*)d_in[3], (const float*)d_in[5],
      (const float*)d_in[11], (const float*)d_in[14], (const float*)d_in[15], (const float*)d_in[19],
      (const float*)d_in[20], (const float*)d_in[23], (const float*)d_in[24], (const float*)d_in[28],
      (const float*)d_in[29], (const float*)d_in[31] };
    unsigned short* dsts[12] = { w_attn_in, w_attn_out,
      w_dir[0][0], w_dir[0][1], w_dir[0][2], w_dir[0][3],
      w_dir[1][0], w_dir[1][1], w_dir[1][2], w_dir[1][3],
      w_bim, w_out };
    int ns[12] = { 786432, 262144, 1048576, 65536, 32768, 524288,
                   1048576, 65536, 32768, 524288, 524288, 5120000 };
    for (int i = 0; i < 12; i++) { a.s[i] = srcs[i]; a.d[i] = dsts[i]; a.n[i] = ns[i]; }
    cvt_many<<<dim3(2500, 12), blk, 0, stream>>>(a);
  }

  // 1. x0 = mel @ mel_w.T + mel_b (f32-in path, K=80)
  gemm_f32in<1, 1><<<dim3(4, 32), blk, 0, stream>>>(mel, mel_w, x0, mel_b,
      4096, 512, 80, 80, 80, 512, nullptr, nullptr, nullptr, nullptr);
  // 2. qkv = x0 @ attn_in_w.T + b
  gemm_bf16<1, 1><<<dim3(12 * 32), blk, 0, stream>>>(x0, w_attn_in, qkv, attn_in_b,
      4096, 1536, 512, 512, 512, 1536, 12, nullptr, nullptr, nullptr);
  // 3. attention
  attn_kernel<<<4096, blk, 0, stream>>>(qkv, attn_o);
  // 4. attnproj -> qkv slot
  gemm_bf16<1, 1><<<dim3(4 * 32), blk, 0, stream>>>(attn_o, w_attn_out, qkv, attn_out_b,
      4096, 512, 512, 512, 512, 512, 4, nullptr, nullptr, nullptr);
  // 5. x1 = LN(x0 + attnproj); x1f = flip(x1) fused
  ln_res_kernel<1><<<1024, blk, 0, stream>>>(x0, qkv, ln1_g, ln1_b, x1, x1f);

  // ---- dual-direction mamba pipeline (blockIdx.y/z = dir) ----
  ScanArgs sa;
  ConvArgs ca;
  for (int dir = 0; dir < 2; dir++) {
    int base = 11 + dir * 9;
    ca.xz[dir] = dir ? xz1 : xz0;
    ca.w[dir]  = (const float*)d_in[base + 1];
    ca.cb[dir] = (const float*)d_in[base + 2];
    ca.xc[dir] = dir ? xc1 : xc0;
    sa.xc[dir]    = dir ? xc1 : xc0;
    sa.dbl[dir]   = dir ? dbl1 : dbl0;
    sa.A_log[dir] = (const float*)d_in[base + 6];
    sa.dt[dir]    = dir ? dtf1 : dtf0;
    sa.Dp[dir]    = (const float*)d_in[base + 7];
    sa.xz[dir]    = dir ? xz1 : xz0;
    sa.hend[dir]  = dir ? hend1 : hend0;
    sa.apr[dir]   = dir ? apr1 : apr0;
    sa.h0[dir]    = dir ? h0s1 : h0s0;
    sa.ys[dir]    = dir ? ysb1 : ysb0;
  }
  // xz = xin @ in_w.T  (dual)
  gemm_bf16<0, 1><<<dim3(16 * 32, 2), blk, 0, stream>>>(x1, w_dir[0][0], xz0, nullptr,
      4096, 2048, 512, 512, 512, 2048, 16, x1f, w_dir[1][0], xz1);
  // conv + silu (dual)
  conv_silu_kernel<<<dim3(2048, 2), blk, 0, stream>>>(ca);
  // dbl = xc @ x_w.T (dual, f32 out for scan numerics)
  gemm_bf16<0, 0><<<dim3(1 * 32, 2), blk, 0, stream>>>(xc0, w_dir[0][1], dbl0, nullptr,
      4096, 64, 1024, 1024, 1024, 64, 1, xc1, w_dir[1][1], dbl1);
  // dt = softplus(dbl[:, :32] @ dt_w.T + dt_b)  (f32-in MFMA path, K=32, dual via grid.z)
  gemm_f32in<2, 0><<<dim3(8, 32, 2), blk, 0, stream>>>(dbl0, (const float*)d_in[15], dtf0, (const float*)d_in[16],
      4096, 1024, 32, 64, 32, 1024, dbl1, (const float*)d_in[24], dtf1, (const float*)d_in[25]);
  // selective scan (dual; dt precomputed; gate + output-flip fused into p3)
  scan_p1<<<dim3(512, 2), blk, 0, stream>>>(sa);
  scan_p2<<<dim3(128, 2), blk, 0, stream>>>(sa);
  scan_p3<<<dim3(512, 2), blk, 0, stream>>>(sa);
  // mamba out proj (dual) -> mout cols [dir*512, +512)
  gemm_bf16<0, 1><<<dim3(4 * 32, 2), blk, 0, stream>>>(ysb0, w_dir[0][3], mout, nullptr,
      4096, 512, 1024, 1024, 1024, 1024, 4, ysb1, w_dir[1][3], mout + 512);

  // m = mout @ bim_w.T + bim_b
  gemm_bf16<1, 1><<<dim3(4 * 32), blk, 0, stream>>>(mout, w_bim, minter, bim_b,
      4096, 512, 1024, 1024, 1024, 512, 4, nullptr, nullptr, nullptr);
  // x2 = LN(x1 + m)
  ln_res_kernel<0><<<1024, blk, 0, stream>>>(x1, minter, ln2_g, ln2_b, x2, nullptr);
  // logits = x2 @ out_w.T + out_b  (overwrites all of d_out; nontemporal f32 stores)
  gemm_bf16<1, 0><<<dim3(79 * 32), blk, 0, stream>>>(x2, w_out, ob, out_b,
      4096, 10000, 512, 512, 512, 10000, 79, nullptr, nullptr, nullptr);
}

// Round 10
// 388.652 us; speedup vs baseline: 1.1037x; 1.1037x over previous
//
#include <hip/hip_runtime.h>
#include <hip/hip_bf16.h>
#include <math.h>

// Model dims
#define SEQ 2048
// B=2, DM=512, DI=1024, N=16, K=4, R=32, H=8, V=10000

typedef __attribute__((ext_vector_type(4))) float f32x4;
typedef __attribute__((ext_vector_type(2))) float f32x2;
typedef __attribute__((ext_vector_type(8))) short bf16x8s;
typedef __attribute__((ext_vector_type(8))) unsigned short ushort8;
typedef __attribute__((ext_vector_type(2))) unsigned int uint2v;

__device__ __forceinline__ short f2bf(float f) {
  union { float f; unsigned u; } c; c.f = f;
  unsigned u = c.u;
  u += 0x7fffu + ((u >> 16) & 1u);   // RNE
  return (short)(u >> 16);
}
__device__ __forceinline__ float bf2f(unsigned short u) {
  union { unsigned u; float f; } c; c.u = ((unsigned)u) << 16; return c.f;
}

__device__ __forceinline__ void lds_load16(const void* g, void* s) {
  __builtin_amdgcn_global_load_lds(
      (const __attribute__((address_space(1))) void*)g,
      (__attribute__((address_space(3))) void*)s, 16, 0, 0);
}

// =================== bf16 MFMA GEMM: C[M,N] = A[M,K] @ B[N,K]^T ===================
// A,B bf16 (K%64==0, lda/ldb %8==0, M%512==0, N%4==0). nbm = M/128 must be %4.
// EPI: 0 none, 1 +bias. OUTBF: 1 -> bf16 C, 0 -> f32 C.
// blockIdx.y==1 selects the A1/B1/C1 tensor set (dual-direction launches).
// Pipeline (T3+T4): STAGE(t+1) issued first, then counted s_waitcnt vmcnt(8),
// barrier, ds_read+MFMA, barrier. XOR-chunk swizzled LDS; LDS-staged epilogue.
// Block order: bijective XCD chunks + 4-bm supertiles (bm-inner, bn-outer).
template<int EPI, int OUTBF>
__launch_bounds__(256)
__global__ void gemm_bf16(const unsigned short* A, const unsigned short* B,
                          void* Cv, const float* __restrict__ bias,
                          int M, int N, int K, int lda, int ldb, int ldc, int nbn,
                          const unsigned short* A1, const unsigned short* B1, void* C1) {
  __shared__ char smem[67584];   // 2x(16KB A + 16KB B) dbuf; 128x132 f32 epilogue tile

  if (blockIdx.y) { A = A1; B = B1; Cv = C1; }

  // bijective XCD chunk swizzle (m204)
  const int nwg = gridDim.x;
  const int g = blockIdx.x;
  const int q = nwg >> 3, r = nwg & 7;
  const int xcd = g & 7, cidx = g >> 3;
  const int wg = (xcd < r ? xcd * (q + 1) : r * (q + 1) + (xcd - r) * q) + cidx;
  // 4-bm supertile order: bm fastest within group of 4, then bn, then bm-group
  const int sup = nbn << 2;
  const int bmg = wg / sup, rem = wg % sup;
  const int bn = rem >> 2;
  const int bm = (bmg << 2) + (rem & 3);
  const int m0 = bm * 128, n0 = bn * 128;

  const int tid = threadIdx.x, lane = tid & 63, wave = tid >> 6;
  const int wr = (wave >> 1) * 64, wc = (wave & 1) * 64;
  const int fr = lane & 15, fq = lane >> 4;
  const int srow = tid >> 3;   // 0..31
  const int scc  = tid & 7;    // column chunk 0..7 (8 bf16 each)

  f32x4 acc[4][4] = {};
  const int nkt = K >> 6;

  auto STAGE = [&](int buf, int kt) {
    const int k0 = kt << 6;
    unsigned short* sAb = (unsigned short*)(smem + buf * 32768);
    unsigned short* sBb = (unsigned short*)(smem + buf * 32768 + 16384);
    #pragma unroll
    for (int j = 0; j < 4; j++) {
      int lrow = j * 32 + srow;
      int gcol = (scc ^ (lrow & 7)) * 8;
      lds_load16(A + (size_t)(m0 + lrow) * lda + k0 + gcol, &sAb[(j * 256 + wave * 64) * 8]);
    }
    #pragma unroll
    for (int j = 0; j < 4; j++) {
      int lrow = j * 32 + srow;
      int gcol = (scc ^ (lrow & 7)) * 8;
      int grow = n0 + lrow; if (grow >= N) grow = N - 1;   // clamp; junk never stored
      lds_load16(B + (size_t)grow * ldb + k0 + gcol, &sBb[(j * 256 + wave * 64) * 8]);
    }
  };

  STAGE(0, 0);

  int cur = 0;
  for (int kt = 0; kt < nkt; kt++) {
    if (kt + 1 < nkt) {
      STAGE(cur ^ 1, kt + 1);                           // 8 new loads in flight
      asm volatile("s_waitcnt vmcnt(8)" ::: "memory");  // previous stage landed (wave-local)
    } else {
      asm volatile("s_waitcnt vmcnt(0)" ::: "memory");  // last tile: full drain
    }
    __builtin_amdgcn_s_barrier();                       // all waves' stage landed
    __builtin_amdgcn_sched_barrier(0);
    const unsigned short* As = (const unsigned short*)(smem + cur * 32768);
    const unsigned short* Bs = (const unsigned short*)(smem + cur * 32768 + 16384);
    #pragma unroll
    for (int ks = 0; ks < 2; ks++) {
      bf16x8s af[4], bfv[4];
      #pragma unroll
      for (int i = 0; i < 4; i++) {
        int ra = wr + i * 16 + fr;
        af[i] = *(const bf16x8s*)&As[ra * 64 + (((ks << 2) + fq) ^ (ra & 7)) * 8];
      }
      #pragma unroll
      for (int i = 0; i < 4; i++) {
        int rb = wc + i * 16 + fr;
        bfv[i] = *(const bf16x8s*)&Bs[rb * 64 + (((ks << 2) + fq) ^ (rb & 7)) * 8];
      }
      #pragma unroll
      for (int i = 0; i < 4; i++)
        #pragma unroll
        for (int j = 0; j < 4; j++)
          acc[i][j] = __builtin_amdgcn_mfma_f32_16x16x32_bf16(af[i], bfv[j], acc[i][j], 0, 0, 0);
    }
    __builtin_amdgcn_s_barrier();   // all reads of cur done -> next STAGE may overwrite it
    cur ^= 1;
  }

  // ---- epilogue: stage f32 tile in LDS, write coalesced ----
  float* ct = (float*)smem;   // [128][132]
  #pragma unroll
  for (int i = 0; i < 4; i++)
    #pragma unroll
    for (int j = 0; j < 4; j++)
      #pragma unroll
      for (int r4 = 0; r4 < 4; r4++)
        ct[(wr + i * 16 + fq * 4 + r4) * 132 + wc + j * 16 + fr] = acc[i][j][r4];
  __syncthreads();
  const int half = lane >> 5;
  const int col4 = (lane & 31) * 4;
  const int cn = n0 + col4;
  #pragma unroll
  for (int it = 0; it < 16; it++) {
    int row = wave * 32 + it * 2 + half;
    f32x4 v = *(const f32x4*)&ct[row * 132 + col4];
    if (cn < N) {
      if (EPI >= 1) {
        f32x4 b4 = *(const f32x4*)&bias[cn];
        #pragma unroll
        for (int j = 0; j < 4; j++) v[j] += b4[j];
      }
      if (OUTBF) {
        unsigned short h0 = (unsigned short)f2bf(v[0]), h1 = (unsigned short)f2bf(v[1]);
        unsigned short h2 = (unsigned short)f2bf(v[2]), h3 = (unsigned short)f2bf(v[3]);
        uint2v o = { (unsigned)h0 | ((unsigned)h1 << 16), (unsigned)h2 | ((unsigned)h3 << 16) };
        *(uint2v*)((unsigned short*)Cv + (size_t)(m0 + row) * ldc + cn) = o;
      } else {
        float* dst = (float*)Cv + (size_t)(m0 + row) * ldc + cn;
        if (EPI == 1) __builtin_nontemporal_store(v, (f32x4*)dst);  // final logits: stream past L2
        else          *(f32x4*)dst = v;
      }
    }
  }
}

// =================== dt matvec: dt[m,d] = softplus(sum_{r<32} dbl[m,r]*dtw[d,r] + b[d]) ===================
// 512 threads/block, each thread owns 2 d-rows of dt_w in registers, 16 m per block.
// dbl-row loads are wave-uniform (broadcast, L2-hit); stores coalesced f32x2.
__launch_bounds__(512)
__global__ void dt_kernel(const float* __restrict__ dbl0, const float* __restrict__ dtw0,
                          const float* __restrict__ dtb0, float* __restrict__ out0,
                          const float* __restrict__ dbl1, const float* __restrict__ dtw1,
                          const float* __restrict__ dtb1, float* __restrict__ out1) {
  const int dir = blockIdx.y;
  const float* dbl = dir ? dbl1 : dbl0;
  const float* dtw = dir ? dtw1 : dtw0;
  const float* dtb = dir ? dtb1 : dtb0;
  float* out = dir ? out1 : out0;
  const int t = threadIdx.x;        // 0..511
  const int d0 = t * 2;
  const int m0 = blockIdx.x * 16;
  float w0[32], w1[32];
  #pragma unroll
  for (int qq = 0; qq < 8; qq++) {
    f32x4 v0 = *(const f32x4*)(dtw + (size_t)d0 * 32 + qq * 4);
    f32x4 v1 = *(const f32x4*)(dtw + (size_t)(d0 + 1) * 32 + qq * 4);
    #pragma unroll
    for (int j = 0; j < 4; j++) { w0[qq * 4 + j] = v0[j]; w1[qq * 4 + j] = v1[j]; }
  }
  const float b0 = dtb[d0], b1 = dtb[d0 + 1];
  for (int mi = 0; mi < 16; mi++) {
    const float* dr = dbl + (size_t)(m0 + mi) * 64;
    float a0 = b0, a1 = b1;
    #pragma unroll
    for (int qq = 0; qq < 8; qq++) {
      f32x4 v = *(const f32x4*)(dr + qq * 4);
      #pragma unroll
      for (int j = 0; j < 4; j++) { a0 += v[j] * w0[qq * 4 + j]; a1 += v[j] * w1[qq * 4 + j]; }
    }
    a0 = fmaxf(a0, 0.f) + log1pf(__expf(-fabsf(a0)));   // softplus
    a1 = fmaxf(a1, 0.f) + log1pf(__expf(-fabsf(a1)));
    f32x2 o = { a0, a1 };
    *(f32x2*)(out + (size_t)(m0 + mi) * 1024 + d0) = o;
  }
}

// =================== weight f32 -> bf16 conversion (12 tensors, one launch) ===================
struct CvtArgs { const float* s[12]; unsigned short* d[12]; int n[12]; };
__global__ void cvt_many(CvtArgs a) {
  int y = blockIdx.y;
  int i = (blockIdx.x * 256 + threadIdx.x) * 8;
  if (i >= a.n[y]) return;
  const float* s = a.s[y];
  f32x4 v0 = *(const f32x4*)(s + i);
  f32x4 v1 = *(const f32x4*)(s + i + 4);
  ushort8 o = { (unsigned short)f2bf(v0[0]), (unsigned short)f2bf(v0[1]),
                (unsigned short)f2bf(v0[2]), (unsigned short)f2bf(v0[3]),
                (unsigned short)f2bf(v1[0]), (unsigned short)f2bf(v1[1]),
                (unsigned short)f2bf(v1[2]), (unsigned short)f2bf(v1[3]) };
  *(ushort8*)(a.d[y] + i) = o;
}

// =================== K-pad f32->bf16: rows x 80 f32 -> rows x 128 bf16 (cols 80..127 = 0) ===================
__global__ void cvt_pad(const float* __restrict__ s0, unsigned short* __restrict__ d0, int r0,
                        const float* __restrict__ s1, unsigned short* __restrict__ d1, int r1) {
  int y = blockIdx.y;
  const float* s = y ? s1 : s0;
  unsigned short* d = y ? d1 : d0;
  int rows = y ? r1 : r0;
  int idx = blockIdx.x * 256 + threadIdx.x;
  int c = idx & 15, row = idx >> 4;
  if (row >= rows) return;
  ushort8 o = { 0, 0, 0, 0, 0, 0, 0, 0 };
  if (c < 10) {
    f32x4 v0 = *(const f32x4*)(s + (size_t)row * 80 + c * 8);
    f32x4 v1 = *(const f32x4*)(s + (size_t)row * 80 + c * 8 + 4);
    o[0] = (unsigned short)f2bf(v0[0]); o[1] = (unsigned short)f2bf(v0[1]);
    o[2] = (unsigned short)f2bf(v0[2]); o[3] = (unsigned short)f2bf(v0[3]);
    o[4] = (unsigned short)f2bf(v1[0]); o[5] = (unsigned short)f2bf(v1[1]);
    o[6] = (unsigned short)f2bf(v1[2]); o[7] = (unsigned short)f2bf(v1[3]);
  }
  *(ushort8*)(d + (size_t)row * 128 + c * 8) = o;
}

// =================== tiny attention (L=2) over bf16 qkv ===================
__global__ void attn_kernel(const unsigned short* __restrict__ qkv, unsigned short* __restrict__ o) {
  int gw = blockIdx.x * 4 + (threadIdx.x >> 6);
  int lane = threadIdx.x & 63;
  int n = gw >> 3, h = gw & 7;
  size_t r0 = (size_t)n * 1536 + h * 64 + lane;
  size_t r1 = (size_t)(SEQ + n) * 1536 + h * 64 + lane;
  float q0 = bf2f(qkv[r0]), k0 = bf2f(qkv[r0 + 512]), v0 = bf2f(qkv[r0 + 1024]);
  float q1 = bf2f(qkv[r1]), k1 = bf2f(qkv[r1 + 512]), v1 = bf2f(qkv[r1 + 1024]);
  float s00 = q0 * k0, s01 = q0 * k1, s10 = q1 * k0, s11 = q1 * k1;
  #pragma unroll
  for (int off = 32; off > 0; off >>= 1) {
    s00 += __shfl_xor(s00, off);
    s01 += __shfl_xor(s01, off);
    s10 += __shfl_xor(s10, off);
    s11 += __shfl_xor(s11, off);
  }
  const float sc = 0.125f;
  s00 *= sc; s01 *= sc; s10 *= sc; s11 *= sc;
  float mx0 = fmaxf(s00, s01), mx1 = fmaxf(s10, s11);
  float e00 = __expf(s00 - mx0), e01 = __expf(s01 - mx0);
  float e10 = __expf(s10 - mx1), e11 = __expf(s11 - mx1);
  float i0 = 1.f / (e00 + e01), i1 = 1.f / (e10 + e11);
  size_t w0 = (size_t)n * 512 + h * 64 + lane;
  size_t w1 = (size_t)(SEQ + n) * 512 + h * 64 + lane;
  o[w0] = (unsigned short)f2bf((e00 * v0 + e01 * v1) * i0);
  o[w1] = (unsigned short)f2bf((e10 * v0 + e11 * v1) * i1);
}

// =================== LN(a+b) over 512, bf16 in/out; DUAL: also write time-flipped copy ===================
template<int DUAL>
__global__ void ln_res_kernel(const unsigned short* __restrict__ a, const unsigned short* __restrict__ b,
                              const float* __restrict__ g, const float* __restrict__ be,
                              unsigned short* __restrict__ out, unsigned short* __restrict__ out2) {
  int row = blockIdx.x * 4 + (threadIdx.x >> 6);
  int lane = threadIdx.x & 63;
  ushort8 va = *(const ushort8*)(a + (size_t)row * 512 + lane * 8);
  ushort8 vb = *(const ushort8*)(b + (size_t)row * 512 + lane * 8);
  float v[8];
  #pragma unroll
  for (int j = 0; j < 8; j++) v[j] = bf2f(va[j]) + bf2f(vb[j]);
  float s = 0.f, s2 = 0.f;
  #pragma unroll
  for (int j = 0; j < 8; j++) { s += v[j]; s2 += v[j] * v[j]; }
  #pragma unroll
  for (int off = 32; off > 0; off >>= 1) { s += __shfl_xor(s, off); s2 += __shfl_xor(s2, off); }
  float mu = s * (1.f / 512.f);
  float var = s2 * (1.f / 512.f) - mu * mu;
  float rs = rsqrtf(var + 1e-5f);
  const float* pg = g + lane * 8;
  const float* pe = be + lane * 8;
  ushort8 o;
  #pragma unroll
  for (int j = 0; j < 8; j++) o[j] = (unsigned short)f2bf((v[j] - mu) * rs * pg[j] + pe[j]);
  *(ushort8*)(out + (size_t)row * 512 + lane * 8) = o;
  if (DUAL) {
    int t = row & (SEQ - 1), bb = row >> 11;
    int frow = (bb << 11) | (SEQ - 1 - t);
    *(ushort8*)(out2 + (size_t)frow * 512 + lane * 8) = o;
  }
}

// =================== depthwise causal conv(K=4)+silu, dual-direction ===================
struct ConvArgs {
  const unsigned short* xz[2];
  const float* w[2];
  const float* cb[2];
  unsigned short* xc[2];
};
__global__ void conv_silu_kernel(ConvArgs a) {
  int dir = blockIdx.y;
  int idx = blockIdx.x * 256 + threadIdx.x;     // over B*S*(DI/8) = 524288
  int dc = (idx & 127) * 8;
  int t  = (idx >> 7) & (SEQ - 1);
  int b  = idx >> 18;
  const float* w = a.w[dir];
  f32x4 wv[8];
  #pragma unroll
  for (int j = 0; j < 8; j++) wv[j] = *(const f32x4*)(w + (dc + j) * 4);
  float acc[8];
  f32x4 cb0 = *(const f32x4*)(a.cb[dir] + dc), cb1 = *(const f32x4*)(a.cb[dir] + dc + 4);
  #pragma unroll
  for (int j = 0; j < 4; j++) { acc[j] = cb0[j]; acc[4 + j] = cb1[j]; }
  const unsigned short* base = a.xz[dir] + ((size_t)b * SEQ) * 2048 + dc;
  #pragma unroll
  for (int k = 0; k < 4; k++) {
    int tt = t - 3 + k;
    if (tt >= 0) {
      ushort8 xv = *(const ushort8*)(base + (size_t)tt * 2048);
      #pragma unroll
      for (int j = 0; j < 8; j++) acc[j] += wv[j][k] * bf2f(xv[j]);
    }
  }
  ushort8 o;
  #pragma unroll
  for (int j = 0; j < 8; j++) {
    float v = acc[j];
    o[j] = (unsigned short)f2bf(v / (1.f + __expf(-v)));
  }
  *(ushort8*)(a.xc[dir] + (size_t)idx * 8) = o;
}

// =================== chunked selective scan, dual-direction (dt from matvec, gate+flip fused) ===================
#define CL 32
#define NC 64

struct ScanArgs {
  const unsigned short* xc[2];
  const float* dbl[2];
  const float* A_log[2];
  const float* dt[2];       // precomputed softplus(dt) f32, (B*S, DI)
  const float* Dp[2];
  const unsigned short* xz[2];
  float* hend[2];
  float* apr[2];
  float* h0[2];
  unsigned short* ys[2];
};

__global__ void scan_p1(ScanArgs s) {
  int dir = blockIdx.y;
  int tid = blockIdx.x * 256 + threadIdx.x;   // B*NC*DI = 131072
  int d = tid & 1023;
  int c = (tid >> 10) & (NC - 1);
  int b = tid >> 16;
  float A[16];
  #pragma unroll
  for (int q = 0; q < 4; q++) {
    f32x4 v = *(const f32x4*)(s.A_log[dir] + d * 16 + q * 4);
    #pragma unroll
    for (int j = 0; j < 4; j++) A[q * 4 + j] = -__expf(v[j]);
  }
  float h[16] = {};
  float ap[16];
  #pragma unroll
  for (int n = 0; n < 16; n++) ap[n] = 1.f;
  const unsigned short* xcp = s.xc[dir] + ((size_t)b * SEQ) * 1024 + d;
  const float* dtp = s.dt[dir] + ((size_t)b * SEQ) * 1024 + d;
  const float* dbp = s.dbl[dir] + ((size_t)b * SEQ) * 64;
  const int t0 = c * CL;
  for (int t = t0; t < t0 + CL; t++) {
    const float* dr = dbp + (size_t)t * 64;
    float dtv = dtp[(size_t)t * 1024];
    float dx = dtv * bf2f(xcp[(size_t)t * 1024]);
    float Bv[16];
    #pragma unroll
    for (int q = 0; q < 4; q++) {
      f32x4 v = *(const f32x4*)(dr + 32 + q * 4);
      #pragma unroll
      for (int j = 0; j < 4; j++) Bv[q * 4 + j] = v[j];
    }
    #pragma unroll
    for (int n = 0; n < 16; n++) {
      float e = __expf(dtv * A[n]);
      h[n] = e * h[n] + dx * Bv[n];
      ap[n] *= e;
    }
  }
  size_t o = ((size_t)((b * NC + c) * 1024 + d)) * 16;
  #pragma unroll
  for (int q = 0; q < 4; q++) {
    f32x4 vh = { h[q * 4], h[q * 4 + 1], h[q * 4 + 2], h[q * 4 + 3] };
    f32x4 va = { ap[q * 4], ap[q * 4 + 1], ap[q * 4 + 2], ap[q * 4 + 3] };
    *(f32x4*)(s.hend[dir] + o + q * 4) = vh;
    *(f32x4*)(s.apr[dir] + o + q * 4) = va;
  }
}

__global__ void scan_p2(ScanArgs s) {
  int dir = blockIdx.y;
  int tid = blockIdx.x * 256 + threadIdx.x;   // B*DI*N = 32768
  int n = tid & 15;
  int d = (tid >> 4) & 1023;
  int b = tid >> 14;
  const float* hend = s.hend[dir];
  const float* apr  = s.apr[dir];
  float* h0 = s.h0[dir];
  float h = 0.f;
  for (int c = 0; c < NC; c++) {
    size_t idx = ((size_t)((b * NC + c) * 1024 + d)) * 16 + n;
    h0[idx] = h;
    h = apr[idx] * h + hend[idx];
  }
}

// p3: recompute with h0, emit gated output, write (dir-1 time-flipped)
__global__ void scan_p3(ScanArgs s) {
  int dir = blockIdx.y;
  int tid = blockIdx.x * 256 + threadIdx.x;   // B*NC*DI = 131072
  int d = tid & 1023;
  int c = (tid >> 10) & (NC - 1);
  int b = tid >> 16;
  float A[16];
  #pragma unroll
  for (int q = 0; q < 4; q++) {
    f32x4 v = *(const f32x4*)(s.A_log[dir] + d * 16 + q * 4);
    #pragma unroll
    for (int j = 0; j < 4; j++) A[q * 4 + j] = -__expf(v[j]);
  }
  const float Dv = s.Dp[dir][d];
  float h[16];
  size_t o = ((size_t)((b * NC + c) * 1024 + d)) * 16;
  #pragma unroll
  for (int q = 0; q < 4; q++) {
    f32x4 v = *(const f32x4*)(s.h0[dir] + o + q * 4);
    #pragma unroll
    for (int j = 0; j < 4; j++) h[q * 4 + j] = v[j];
  }
  const unsigned short* xcp = s.xc[dir] + ((size_t)b * SEQ) * 1024 + d;
  const float* dtp = s.dt[dir] + ((size_t)b * SEQ) * 1024 + d;
  const unsigned short* zp  = s.xz[dir] + ((size_t)b * SEQ) * 2048 + 1024 + d;
  const float* dbp = s.dbl[dir] + ((size_t)b * SEQ) * 64;
  unsigned short* ysp = s.ys[dir] + ((size_t)b * SEQ) * 1024 + d;
  const int t0 = c * CL;
  for (int t = t0; t < t0 + CL; t++) {
    const float* dr = dbp + (size_t)t * 64;
    float dtv = dtp[(size_t)t * 1024];
    float xcv = bf2f(xcp[(size_t)t * 1024]);
    float dx = dtv * xcv;
    float Bv[16], Cv[16];
    #pragma unroll
    for (int q = 0; q < 4; q++) {
      f32x4 v = *(const f32x4*)(dr + 32 + q * 4);
      f32x4 w = *(const f32x4*)(dr + 48 + q * 4);
      #pragma unroll
      for (int j = 0; j < 4; j++) { Bv[q * 4 + j] = v[j]; Cv[q * 4 + j] = w[j]; }
    }
    float y = 0.f;
    #pragma unroll
    for (int n = 0; n < 16; n++) {
      float e = __expf(dtv * A[n]);
      h[n] = e * h[n] + dx * Bv[n];
      y += h[n] * Cv[n];
    }
    // gate: (y + xc*D) * silu(z)
    float z = bf2f(zp[(size_t)t * 2048]);
    float out = (y + xcv * Dv) * (z / (1.f + __expf(-z)));
    int tw = dir ? (SEQ - 1 - t) : t;
    ysp[(size_t)tw * 1024] = (unsigned short)f2bf(out);
  }
}

extern "C" void kernel_launch(void* const* d_in, const int* in_sizes, int n_in,
                              void* d_out, int out_size, void* d_ws, size_t ws_size,
                              hipStream_t stream) {
  (void)in_sizes; (void)n_in; (void)out_size; (void)ws_size;
  const float* mel        = (const float*)d_in[0];
  const float* mel_w      = (const float*)d_in[1];
  const float* mel_b      = (const float*)d_in[2];
  const float* attn_in_b  = (const float*)d_in[4];
  const float* attn_out_b = (const float*)d_in[6];
  const float* ln1_g = (const float*)d_in[7];
  const float* ln1_b = (const float*)d_in[8];
  const float* ln2_g = (const float*)d_in[9];
  const float* ln2_b = (const float*)d_in[10];
  const float* bim_b = (const float*)d_in[30];
  const float* out_b = (const float*)d_in[32];

  char* wsb = (char*)d_ws;
  char* obb = (char*)d_out;

  // ---- bf16 weights in ws (byte offsets) ----
  unsigned short* w_attn_in  = (unsigned short*)(wsb + 0);          // 786432
  unsigned short* w_attn_out = (unsigned short*)(wsb + 1572864);    // 262144
  unsigned short* w_dir[2][4];
  for (int dir = 0; dir < 2; dir++) {
    size_t base = 2097152 + (size_t)dir * 3342336;
    w_dir[dir][0] = (unsigned short*)(wsb + base);                  // in_w
    w_dir[dir][1] = (unsigned short*)(wsb + base + 2097152);        // x_w
    w_dir[dir][2] = (unsigned short*)(wsb + base + 2228224);        // (spare)
    w_dir[dir][3] = (unsigned short*)(wsb + base + 2293760);        // out_w
  }
  unsigned short* w_bim = (unsigned short*)(wsb + 8781824);         // 524288
  unsigned short* w_out = (unsigned short*)(wsb + 9830400);         // 5120000

  // ---- bf16 activations in ws ----
  unsigned short* x0     = (unsigned short*)(wsb + 20971520);
  unsigned short* x1     = (unsigned short*)(wsb + 25165824);
  unsigned short* x1f    = (unsigned short*)(wsb + 29360128);
  unsigned short* attn_o = (unsigned short*)(wsb + 33554432);
  unsigned short* xc0    = (unsigned short*)(wsb + 37748736);  // 8.39MB
  unsigned short* ysb0   = (unsigned short*)(wsb + 46137344);  // 8.39MB
  unsigned short* mout   = (unsigned short*)(wsb + 62914560);  // 8.39MB
  unsigned short* minter = (unsigned short*)(wsb + 71303168);
  unsigned short* x2     = (unsigned short*)(wsb + 75497472);
  float*          dbl0   = (float*)(wsb + 79691776);           // 1.05MB
  unsigned short* melp   = (unsigned short*)(wsb + 80740352);  // 4096x128 bf16 = 1.05MB
  unsigned short* melwp  = (unsigned short*)(wsb + 81788928);  // 512x128 bf16 = 131072B

  // ---- d_out scratch (dead until final GEMM overwrites all; 163.84MB) ----
  unsigned short* qkv  = (unsigned short*)(obb + 0);           // 12.58MB
  unsigned short* xz0  = (unsigned short*)(obb + 12582912);    // 16.78MB
  unsigned short* xz1  = (unsigned short*)(obb + 29360128);    // 16.78MB
  unsigned short* xc1  = (unsigned short*)(obb + 46137344);    // 8.39MB
  unsigned short* ysb1 = (unsigned short*)(obb + 54525952);    // 8.39MB
  float* hend0 = (float*)(obb + 62914560);                     // 8.39MB
  float* hend1 = (float*)(obb + 71303168);
  float* apr0  = (float*)(obb + 79691776);
  float* apr1  = (float*)(obb + 88080384);
  float* h0s0  = (float*)(obb + 96468992);
  float* h0s1  = (float*)(obb + 104857600);
  float* dbl1  = (float*)(obb + 113246208);                    // 1.05MB
  float* dtf0  = (float*)(obb + 114294784);                    // 16.78MB
  float* dtf1  = (float*)(obb + 131072000);                    // 16.78MB -> ends 147.85MB
  float* ob    = (float*)d_out;

  dim3 blk(256);

  // 0. convert weights to bf16; pad-convert mel + mel_w to K=128 bf16
  {
    CvtArgs a;
    const float* srcs[12] = { (const float*)d_in[3], (const float*)d_in[5],
      (const float*)d_in[11], (const float*)d_in[14], (const float*)d_in[15], (const float*)d_in[19],
      (const float*)d_in[20], (const float*)d_in[23], (const float*)d_in[24], (const float*)d_in[28],
      (const float*)d_in[29], (const float*)d_in[31] };
    unsigned short* dsts[12] = { w_attn_in, w_attn_out,
      w_dir[0][0], w_dir[0][1], w_dir[0][2], w_dir[0][3],
      w_dir[1][0], w_dir[1][1], w_dir[1][2], w_dir[1][3],
      w_bim, w_out };
    int ns[12] = { 786432, 262144, 1048576, 65536, 32768, 524288,
                   1048576, 65536, 32768, 524288, 524288, 5120000 };
    for (int i = 0; i < 12; i++) { a.s[i] = srcs[i]; a.d[i] = dsts[i]; a.n[i] = ns[i]; }
    cvt_many<<<dim3(2500, 12), blk, 0, stream>>>(a);
    cvt_pad<<<dim3(256, 2), blk, 0, stream>>>(mel, melp, 4096, mel_w, melwp, 512);
  }

  // 1. x0 = melp @ melwp.T + mel_b  (bf16 path, K=128 zero-padded)
  gemm_bf16<1, 1><<<dim3(4 * 32), blk, 0, stream>>>(melp, melwp, x0, mel_b,
      4096, 512, 128, 128, 128, 512, 4, nullptr, nullptr, nullptr);
  // 2. qkv = x0 @ attn_in_w.T + b
  gemm_bf16<1, 1><<<dim3(12 * 32), blk, 0, stream>>>(x0, w_attn_in, qkv, attn_in_b,
      4096, 1536, 512, 512, 512, 1536, 12, nullptr, nullptr, nullptr);
  // 3. attention
  attn_kernel<<<4096, blk, 0, stream>>>(qkv, attn_o);
  // 4. attnproj -> qkv slot
  gemm_bf16<1, 1><<<dim3(4 * 32), blk, 0, stream>>>(attn_o, w_attn_out, qkv, attn_out_b,
      4096, 512, 512, 512, 512, 512, 4, nullptr, nullptr, nullptr);
  // 5. x1 = LN(x0 + attnproj); x1f = flip(x1) fused
  ln_res_kernel<1><<<1024, blk, 0, stream>>>(x0, qkv, ln1_g, ln1_b, x1, x1f);

  // ---- dual-direction mamba pipeline (blockIdx.y = dir) ----
  ScanArgs sa;
  ConvArgs ca;
  for (int dir = 0; dir < 2; dir++) {
    int base = 11 + dir * 9;
    ca.xz[dir] = dir ? xz1 : xz0;
    ca.w[dir]  = (const float*)d_in[base + 1];
    ca.cb[dir] = (const float*)d_in[base + 2];
    ca.xc[dir] = dir ? xc1 : xc0;
    sa.xc[dir]    = dir ? xc1 : xc0;
    sa.dbl[dir]   = dir ? dbl1 : dbl0;
    sa.A_log[dir] = (const float*)d_in[base + 6];
    sa.dt[dir]    = dir ? dtf1 : dtf0;
    sa.Dp[dir]    = (const float*)d_in[base + 7];
    sa.xz[dir]    = dir ? xz1 : xz0;
    sa.hend[dir]  = dir ? hend1 : hend0;
    sa.apr[dir]   = dir ? apr1 : apr0;
    sa.h0[dir]    = dir ? h0s1 : h0s0;
    sa.ys[dir]    = dir ? ysb1 : ysb0;
  }
  // xz = xin @ in_w.T  (dual)
  gemm_bf16<0, 1><<<dim3(16 * 32, 2), blk, 0, stream>>>(x1, w_dir[0][0], xz0, nullptr,
      4096, 2048, 512, 512, 512, 2048, 16, x1f, w_dir[1][0], xz1);
  // conv + silu (dual)
  conv_silu_kernel<<<dim3(2048, 2), blk, 0, stream>>>(ca);
  // dbl = xc @ x_w.T (dual, f32 out for scan numerics)
  gemm_bf16<0, 0><<<dim3(1 * 32, 2), blk, 0, stream>>>(xc0, w_dir[0][1], dbl0, nullptr,
      4096, 64, 1024, 1024, 1024, 64, 1, xc1, w_dir[1][1], dbl1);
  // dt = softplus(dbl[:, :32] @ dt_w.T + dt_b)  (dedicated f32 matvec, dual)
  dt_kernel<<<dim3(256, 2), dim3(512), 0, stream>>>(
      dbl0, (const float*)d_in[15], (const float*)d_in[16], dtf0,
      dbl1, (const float*)d_in[24], (const float*)d_in[25], dtf1);
  // selective scan (dual; dt precomputed; gate + output-flip fused into p3)
  scan_p1<<<dim3(512, 2), blk, 0, stream>>>(sa);
  scan_p2<<<dim3(128, 2), blk, 0, stream>>>(sa);
  scan_p3<<<dim3(512, 2), blk, 0, stream>>>(sa);
  // mamba out proj (dual) -> mout cols [dir*512, +512)
  gemm_bf16<0, 1><<<dim3(4 * 32, 2), blk, 0, stream>>>(ysb0, w_dir[0][3], mout, nullptr,
      4096, 512, 1024, 1024, 1024, 1024, 4, ysb1, w_dir[1][3], mout + 512);

  // m = mout @ bim_w.T + bim_b
  gemm_bf16<1, 1><<<dim3(4 * 32), blk, 0, stream>>>(mout, w_bim, minter, bim_b,
      4096, 512, 1024, 1024, 1024, 512, 4, nullptr, nullptr, nullptr);
  // x2 = LN(x1 + m)
  ln_res_kernel<0><<<1024, blk, 0, stream>>>(x1, minter, ln2_g, ln2_b, x2, nullptr);
  // logits = x2 @ out_w.T + out_b  (overwrites all of d_out; nontemporal f32 stores)
  gemm_bf16<1, 0><<<dim3(79 * 32), blk, 0, stream>>>(x2, w_out, ob, out_b,
      4096, 10000, 512, 512, 512, 10000, 79, nullptr, nullptr, nullptr);
}

// Round 11
// 353.210 us; speedup vs baseline: 1.2145x; 1.1003x over previous
//
#include <hip/hip_runtime.h>
#include <hip/hip_bf16.h>
#include <math.h>

// Model dims
#define SEQ 2048
// B=2, DM=512, DI=1024, N=16, K=4, R=32, H=8, V=10000

typedef __attribute__((ext_vector_type(4))) float f32x4;
typedef __attribute__((ext_vector_type(2))) float f32x2;
typedef __attribute__((ext_vector_type(8))) short bf16x8s;
typedef __attribute__((ext_vector_type(8))) unsigned short ushort8;
typedef __attribute__((ext_vector_type(2))) unsigned int uint2v;

__device__ __forceinline__ short f2bf(float f) {
  union { float f; unsigned u; } c; c.f = f;
  unsigned u = c.u;
  u += 0x7fffu + ((u >> 16) & 1u);   // RNE
  return (short)(u >> 16);
}
__device__ __forceinline__ float bf2f(unsigned short u) {
  union { unsigned u; float f; } c; c.u = ((unsigned)u) << 16; return c.f;
}

__device__ __forceinline__ void lds_load16(const void* g, void* s) {
  __builtin_amdgcn_global_load_lds(
      (const __attribute__((address_space(1))) void*)g,
      (__attribute__((address_space(3))) void*)s, 16, 0, 0);
}

// =================== bf16 MFMA GEMM: C[M,N] = A[M,K] @ B[N,K]^T ===================
// A,B bf16 (K%64==0, lda/ldb %8==0, M%512==0, N%4==0). nbm = M/128 must be %4.
// EPI: 0 none, 1 +bias. OUTBF: 1 -> bf16 C, 0 -> f32 C.
// blockIdx.y==1 selects the A1/B1/C1 tensor set (dual-direction launches).
// Pipeline (T3+T4): STAGE(t+1) issued first, then counted s_waitcnt vmcnt(8),
// barrier, ds_read+MFMA, barrier. XOR-chunk swizzled LDS; LDS-staged epilogue.
// Block order: bijective XCD chunks + 4-bm supertiles (bm-inner, bn-outer).
template<int EPI, int OUTBF>
__launch_bounds__(256)
__global__ void gemm_bf16(const unsigned short* A, const unsigned short* B,
                          void* Cv, const float* __restrict__ bias,
                          int M, int N, int K, int lda, int ldb, int ldc, int nbn,
                          const unsigned short* A1, const unsigned short* B1, void* C1) {
  __shared__ char smem[67584];   // 2x(16KB A + 16KB B) dbuf; 128x132 f32 epilogue tile

  if (blockIdx.y) { A = A1; B = B1; Cv = C1; }

  // bijective XCD chunk swizzle (m204)
  const int nwg = gridDim.x;
  const int g = blockIdx.x;
  const int q = nwg >> 3, r = nwg & 7;
  const int xcd = g & 7, cidx = g >> 3;
  const int wg = (xcd < r ? xcd * (q + 1) : r * (q + 1) + (xcd - r) * q) + cidx;
  // 4-bm supertile order: bm fastest within group of 4, then bn, then bm-group
  const int sup = nbn << 2;
  const int bmg = wg / sup, rem = wg % sup;
  const int bn = rem >> 2;
  const int bm = (bmg << 2) + (rem & 3);
  const int m0 = bm * 128, n0 = bn * 128;

  const int tid = threadIdx.x, lane = tid & 63, wave = tid >> 6;
  const int wr = (wave >> 1) * 64, wc = (wave & 1) * 64;
  const int fr = lane & 15, fq = lane >> 4;
  const int srow = tid >> 3;   // 0..31
  const int scc  = tid & 7;    // column chunk 0..7 (8 bf16 each)

  f32x4 acc[4][4] = {};
  const int nkt = K >> 6;

  auto STAGE = [&](int buf, int kt) {
    const int k0 = kt << 6;
    unsigned short* sAb = (unsigned short*)(smem + buf * 32768);
    unsigned short* sBb = (unsigned short*)(smem + buf * 32768 + 16384);
    #pragma unroll
    for (int j = 0; j < 4; j++) {
      int lrow = j * 32 + srow;
      int gcol = (scc ^ (lrow & 7)) * 8;
      lds_load16(A + (size_t)(m0 + lrow) * lda + k0 + gcol, &sAb[(j * 256 + wave * 64) * 8]);
    }
    #pragma unroll
    for (int j = 0; j < 4; j++) {
      int lrow = j * 32 + srow;
      int gcol = (scc ^ (lrow & 7)) * 8;
      int grow = n0 + lrow; if (grow >= N) grow = N - 1;   // clamp; junk never stored
      lds_load16(B + (size_t)grow * ldb + k0 + gcol, &sBb[(j * 256 + wave * 64) * 8]);
    }
  };

  STAGE(0, 0);

  int cur = 0;
  for (int kt = 0; kt < nkt; kt++) {
    if (kt + 1 < nkt) {
      STAGE(cur ^ 1, kt + 1);                           // 8 new loads in flight
      asm volatile("s_waitcnt vmcnt(8)" ::: "memory");  // previous stage landed (wave-local)
    } else {
      asm volatile("s_waitcnt vmcnt(0)" ::: "memory");  // last tile: full drain
    }
    __builtin_amdgcn_s_barrier();                       // all waves' stage landed
    __builtin_amdgcn_sched_barrier(0);
    const unsigned short* As = (const unsigned short*)(smem + cur * 32768);
    const unsigned short* Bs = (const unsigned short*)(smem + cur * 32768 + 16384);
    #pragma unroll
    for (int ks = 0; ks < 2; ks++) {
      bf16x8s af[4], bfv[4];
      #pragma unroll
      for (int i = 0; i < 4; i++) {
        int ra = wr + i * 16 + fr;
        af[i] = *(const bf16x8s*)&As[ra * 64 + (((ks << 2) + fq) ^ (ra & 7)) * 8];
      }
      #pragma unroll
      for (int i = 0; i < 4; i++) {
        int rb = wc + i * 16 + fr;
        bfv[i] = *(const bf16x8s*)&Bs[rb * 64 + (((ks << 2) + fq) ^ (rb & 7)) * 8];
      }
      #pragma unroll
      for (int i = 0; i < 4; i++)
        #pragma unroll
        for (int j = 0; j < 4; j++)
          acc[i][j] = __builtin_amdgcn_mfma_f32_16x16x32_bf16(af[i], bfv[j], acc[i][j], 0, 0, 0);
    }
    __builtin_amdgcn_s_barrier();   // all reads of cur done -> next STAGE may overwrite it
    cur ^= 1;
  }

  // ---- epilogue: stage f32 tile in LDS, write coalesced ----
  float* ct = (float*)smem;   // [128][132]
  #pragma unroll
  for (int i = 0; i < 4; i++)
    #pragma unroll
    for (int j = 0; j < 4; j++)
      #pragma unroll
      for (int r4 = 0; r4 < 4; r4++)
        ct[(wr + i * 16 + fq * 4 + r4) * 132 + wc + j * 16 + fr] = acc[i][j][r4];
  __syncthreads();
  const int half = lane >> 5;
  const int col4 = (lane & 31) * 4;
  const int cn = n0 + col4;
  #pragma unroll
  for (int it = 0; it < 16; it++) {
    int row = wave * 32 + it * 2 + half;
    f32x4 v = *(const f32x4*)&ct[row * 132 + col4];
    if (cn < N) {
      if (EPI >= 1) {
        f32x4 b4 = *(const f32x4*)&bias[cn];
        #pragma unroll
        for (int j = 0; j < 4; j++) v[j] += b4[j];
      }
      if (OUTBF) {
        unsigned short h0 = (unsigned short)f2bf(v[0]), h1 = (unsigned short)f2bf(v[1]);
        unsigned short h2 = (unsigned short)f2bf(v[2]), h3 = (unsigned short)f2bf(v[3]);
        uint2v o = { (unsigned)h0 | ((unsigned)h1 << 16), (unsigned)h2 | ((unsigned)h3 << 16) };
        *(uint2v*)((unsigned short*)Cv + (size_t)(m0 + row) * ldc + cn) = o;
      } else {
        float* dst = (float*)Cv + (size_t)(m0 + row) * ldc + cn;
        if (EPI == 1) __builtin_nontemporal_store(v, (f32x4*)dst);  // final logits: stream past L2
        else          *(f32x4*)dst = v;
      }
    }
  }
}

// =================== dt matvec: dt[m,d] = softplus(sum_{r<32} dbl[m,r]*dtw[d,r] + b[d]) ===================
__launch_bounds__(512)
__global__ void dt_kernel(const float* __restrict__ dbl0, const float* __restrict__ dtw0,
                          const float* __restrict__ dtb0, float* __restrict__ out0,
                          const float* __restrict__ dbl1, const float* __restrict__ dtw1,
                          const float* __restrict__ dtb1, float* __restrict__ out1) {
  const int dir = blockIdx.y;
  const float* dbl = dir ? dbl1 : dbl0;
  const float* dtw = dir ? dtw1 : dtw0;
  const float* dtb = dir ? dtb1 : dtb0;
  float* out = dir ? out1 : out0;
  const int t = threadIdx.x;        // 0..511
  const int d0 = t * 2;
  const int m0 = blockIdx.x * 16;
  float w0[32], w1[32];
  #pragma unroll
  for (int qq = 0; qq < 8; qq++) {
    f32x4 v0 = *(const f32x4*)(dtw + (size_t)d0 * 32 + qq * 4);
    f32x4 v1 = *(const f32x4*)(dtw + (size_t)(d0 + 1) * 32 + qq * 4);
    #pragma unroll
    for (int j = 0; j < 4; j++) { w0[qq * 4 + j] = v0[j]; w1[qq * 4 + j] = v1[j]; }
  }
  const float b0 = dtb[d0], b1 = dtb[d0 + 1];
  for (int mi = 0; mi < 16; mi++) {
    const float* dr = dbl + (size_t)(m0 + mi) * 64;
    float a0 = b0, a1 = b1;
    #pragma unroll
    for (int qq = 0; qq < 8; qq++) {
      f32x4 v = *(const f32x4*)(dr + qq * 4);
      #pragma unroll
      for (int j = 0; j < 4; j++) { a0 += v[j] * w0[qq * 4 + j]; a1 += v[j] * w1[qq * 4 + j]; }
    }
    a0 = fmaxf(a0, 0.f) + log1pf(__expf(-fabsf(a0)));   // softplus
    a1 = fmaxf(a1, 0.f) + log1pf(__expf(-fabsf(a1)));
    f32x2 o = { a0, a1 };
    *(f32x2*)(out + (size_t)(m0 + mi) * 1024 + d0) = o;
  }
}

// =================== weight f32 -> bf16 conversion (12 tensors, one launch) ===================
struct CvtArgs { const float* s[12]; unsigned short* d[12]; int n[12]; };
__global__ void cvt_many(CvtArgs a) {
  int y = blockIdx.y;
  int i = (blockIdx.x * 256 + threadIdx.x) * 8;
  if (i >= a.n[y]) return;
  const float* s = a.s[y];
  f32x4 v0 = *(const f32x4*)(s + i);
  f32x4 v1 = *(const f32x4*)(s + i + 4);
  ushort8 o = { (unsigned short)f2bf(v0[0]), (unsigned short)f2bf(v0[1]),
                (unsigned short)f2bf(v0[2]), (unsigned short)f2bf(v0[3]),
                (unsigned short)f2bf(v1[0]), (unsigned short)f2bf(v1[1]),
                (unsigned short)f2bf(v1[2]), (unsigned short)f2bf(v1[3]) };
  *(ushort8*)(a.d[y] + i) = o;
}

// =================== K-pad f32->bf16: rows x 80 f32 -> rows x 128 bf16 (cols 80..127 = 0) ===================
__global__ void cvt_pad(const float* __restrict__ s0, unsigned short* __restrict__ d0, int r0,
                        const float* __restrict__ s1, unsigned short* __restrict__ d1, int r1) {
  int y = blockIdx.y;
  const float* s = y ? s1 : s0;
  unsigned short* d = y ? d1 : d0;
  int rows = y ? r1 : r0;
  int idx = blockIdx.x * 256 + threadIdx.x;
  int c = idx & 15, row = idx >> 4;
  if (row >= rows) return;
  ushort8 o = { 0, 0, 0, 0, 0, 0, 0, 0 };
  if (c < 10) {
    f32x4 v0 = *(const f32x4*)(s + (size_t)row * 80 + c * 8);
    f32x4 v1 = *(const f32x4*)(s + (size_t)row * 80 + c * 8 + 4);
    o[0] = (unsigned short)f2bf(v0[0]); o[1] = (unsigned short)f2bf(v0[1]);
    o[2] = (unsigned short)f2bf(v0[2]); o[3] = (unsigned short)f2bf(v0[3]);
    o[4] = (unsigned short)f2bf(v1[0]); o[5] = (unsigned short)f2bf(v1[1]);
    o[6] = (unsigned short)f2bf(v1[2]); o[7] = (unsigned short)f2bf(v1[3]);
  }
  *(ushort8*)(d + (size_t)row * 128 + c * 8) = o;
}

// =================== tiny attention (L=2) over bf16 qkv ===================
__global__ void attn_kernel(const unsigned short* __restrict__ qkv, unsigned short* __restrict__ o) {
  int gw = blockIdx.x * 4 + (threadIdx.x >> 6);
  int lane = threadIdx.x & 63;
  int n = gw >> 3, h = gw & 7;
  size_t r0 = (size_t)n * 1536 + h * 64 + lane;
  size_t r1 = (size_t)(SEQ + n) * 1536 + h * 64 + lane;
  float q0 = bf2f(qkv[r0]), k0 = bf2f(qkv[r0 + 512]), v0 = bf2f(qkv[r0 + 1024]);
  float q1 = bf2f(qkv[r1]), k1 = bf2f(qkv[r1 + 512]), v1 = bf2f(qkv[r1 + 1024]);
  float s00 = q0 * k0, s01 = q0 * k1, s10 = q1 * k0, s11 = q1 * k1;
  #pragma unroll
  for (int off = 32; off > 0; off >>= 1) {
    s00 += __shfl_xor(s00, off);
    s01 += __shfl_xor(s01, off);
    s10 += __shfl_xor(s10, off);
    s11 += __shfl_xor(s11, off);
  }
  const float sc = 0.125f;
  s00 *= sc; s01 *= sc; s10 *= sc; s11 *= sc;
  float mx0 = fmaxf(s00, s01), mx1 = fmaxf(s10, s11);
  float e00 = __expf(s00 - mx0), e01 = __expf(s01 - mx0);
  float e10 = __expf(s10 - mx1), e11 = __expf(s11 - mx1);
  float i0 = 1.f / (e00 + e01), i1 = 1.f / (e10 + e11);
  size_t w0 = (size_t)n * 512 + h * 64 + lane;
  size_t w1 = (size_t)(SEQ + n) * 512 + h * 64 + lane;
  o[w0] = (unsigned short)f2bf((e00 * v0 + e01 * v1) * i0);
  o[w1] = (unsigned short)f2bf((e10 * v0 + e11 * v1) * i1);
}

// =================== LN(a+b) over 512, bf16 in/out; DUAL: also write time-flipped copy ===================
template<int DUAL>
__global__ void ln_res_kernel(const unsigned short* __restrict__ a, const unsigned short* __restrict__ b,
                              const float* __restrict__ g, const float* __restrict__ be,
                              unsigned short* __restrict__ out, unsigned short* __restrict__ out2) {
  int row = blockIdx.x * 4 + (threadIdx.x >> 6);
  int lane = threadIdx.x & 63;
  ushort8 va = *(const ushort8*)(a + (size_t)row * 512 + lane * 8);
  ushort8 vb = *(const ushort8*)(b + (size_t)row * 512 + lane * 8);
  float v[8];
  #pragma unroll
  for (int j = 0; j < 8; j++) v[j] = bf2f(va[j]) + bf2f(vb[j]);
  float s = 0.f, s2 = 0.f;
  #pragma unroll
  for (int j = 0; j < 8; j++) { s += v[j]; s2 += v[j] * v[j]; }
  #pragma unroll
  for (int off = 32; off > 0; off >>= 1) { s += __shfl_xor(s, off); s2 += __shfl_xor(s2, off); }
  float mu = s * (1.f / 512.f);
  float var = s2 * (1.f / 512.f) - mu * mu;
  float rs = rsqrtf(var + 1e-5f);
  const float* pg = g + lane * 8;
  const float* pe = be + lane * 8;
  ushort8 o;
  #pragma unroll
  for (int j = 0; j < 8; j++) o[j] = (unsigned short)f2bf((v[j] - mu) * rs * pg[j] + pe[j]);
  *(ushort8*)(out + (size_t)row * 512 + lane * 8) = o;
  if (DUAL) {
    int t = row & (SEQ - 1), bb = row >> 11;
    int frow = (bb << 11) | (SEQ - 1 - t);
    *(ushort8*)(out2 + (size_t)frow * 512 + lane * 8) = o;
  }
}

// =================== depthwise causal conv(K=4)+silu, dual-direction ===================
struct ConvArgs {
  const unsigned short* xz[2];
  const float* w[2];
  const float* cb[2];
  unsigned short* xc[2];
};
__global__ void conv_silu_kernel(ConvArgs a) {
  int dir = blockIdx.y;
  int idx = blockIdx.x * 256 + threadIdx.x;     // over B*S*(DI/8) = 524288
  int dc = (idx & 127) * 8;
  int t  = (idx >> 7) & (SEQ - 1);
  int b  = idx >> 18;
  const float* w = a.w[dir];
  f32x4 wv[8];
  #pragma unroll
  for (int j = 0; j < 8; j++) wv[j] = *(const f32x4*)(w + (dc + j) * 4);
  float acc[8];
  f32x4 cb0 = *(const f32x4*)(a.cb[dir] + dc), cb1 = *(const f32x4*)(a.cb[dir] + dc + 4);
  #pragma unroll
  for (int j = 0; j < 4; j++) { acc[j] = cb0[j]; acc[4 + j] = cb1[j]; }
  const unsigned short* base = a.xz[dir] + ((size_t)b * SEQ) * 2048 + dc;
  #pragma unroll
  for (int k = 0; k < 4; k++) {
    int tt = t - 3 + k;
    if (tt >= 0) {
      ushort8 xv = *(const ushort8*)(base + (size_t)tt * 2048);
      #pragma unroll
      for (int j = 0; j < 8; j++) acc[j] += wv[j][k] * bf2f(xv[j]);
    }
  }
  ushort8 o;
  #pragma unroll
  for (int j = 0; j < 8; j++) {
    float v = acc[j];
    o[j] = (unsigned short)f2bf(v / (1.f + __expf(-v)));
  }
  *(ushort8*)(a.xc[dir] + (size_t)idx * 8) = o;
}

// =================== chunked selective scan, dual-direction ===================
// 4 lanes per (b,c,d): lane-quad nq owns 4 of the 16 states -> 4x occupancy.
#define CL 32
#define NC 64

struct ScanArgs {
  const unsigned short* xc[2];
  const float* dbl[2];
  const float* A_log[2];
  const float* dt[2];       // precomputed softplus(dt) f32, (B*S, DI)
  const float* Dp[2];
  const unsigned short* xz[2];
  float* hend[2];
  float* apr[2];
  float* h0[2];
  unsigned short* ys[2];
};

__global__ void scan_p1(ScanArgs s) {
  int dir = blockIdx.y;
  int tid = blockIdx.x * 256 + threadIdx.x;   // over B*NC*DI*4 = 524288
  int nq = tid & 3;
  int d = (tid >> 2) & 1023;
  int c = (tid >> 12) & (NC - 1);
  int b = tid >> 18;
  f32x4 va = *(const f32x4*)(s.A_log[dir] + d * 16 + nq * 4);
  float A[4];
  #pragma unroll
  for (int j = 0; j < 4; j++) A[j] = -__expf(va[j]);
  float h[4] = {};
  float ap[4] = { 1.f, 1.f, 1.f, 1.f };
  const unsigned short* xcp = s.xc[dir] + ((size_t)b * SEQ) * 1024 + d;
  const float* dtp = s.dt[dir] + ((size_t)b * SEQ) * 1024 + d;
  const float* dbp = s.dbl[dir] + ((size_t)b * SEQ) * 64;
  const int t0 = c * CL;
  for (int t = t0; t < t0 + CL; t++) {
    float dtv = dtp[(size_t)t * 1024];
    float dx = dtv * bf2f(xcp[(size_t)t * 1024]);
    f32x4 Bv = *(const f32x4*)(dbp + (size_t)t * 64 + 32 + nq * 4);
    #pragma unroll
    for (int j = 0; j < 4; j++) {
      float e = __expf(dtv * A[j]);
      h[j] = e * h[j] + dx * Bv[j];
      ap[j] *= e;
    }
  }
  size_t o = ((size_t)((b * NC + c) * 1024 + d)) * 16 + nq * 4;
  f32x4 vh = { h[0], h[1], h[2], h[3] };
  f32x4 vap = { ap[0], ap[1], ap[2], ap[3] };
  *(f32x4*)(s.hend[dir] + o) = vh;
  *(f32x4*)(s.apr[dir] + o) = vap;
}

__global__ void scan_p2(ScanArgs s) {
  int dir = blockIdx.y;
  int tid = blockIdx.x * 256 + threadIdx.x;   // B*DI*N = 32768
  int n = tid & 15;
  int d = (tid >> 4) & 1023;
  int b = tid >> 14;
  const float* hend = s.hend[dir];
  const float* apr  = s.apr[dir];
  float* h0 = s.h0[dir];
  float h = 0.f;
  for (int c = 0; c < NC; c++) {
    size_t idx = ((size_t)((b * NC + c) * 1024 + d)) * 16 + n;
    h0[idx] = h;
    h = apr[idx] * h + hend[idx];
  }
}

// p3: recompute with h0, emit gated output, write (dir-1 time-flipped)
__global__ void scan_p3(ScanArgs s) {
  int dir = blockIdx.y;
  int tid = blockIdx.x * 256 + threadIdx.x;   // over B*NC*DI*4 = 524288
  int nq = tid & 3;
  int d = (tid >> 2) & 1023;
  int c = (tid >> 12) & (NC - 1);
  int b = tid >> 18;
  f32x4 va = *(const f32x4*)(s.A_log[dir] + d * 16 + nq * 4);
  float A[4];
  #pragma unroll
  for (int j = 0; j < 4; j++) A[j] = -__expf(va[j]);
  const float Dv = s.Dp[dir][d];
  size_t o = ((size_t)((b * NC + c) * 1024 + d)) * 16 + nq * 4;
  f32x4 h4 = *(const f32x4*)(s.h0[dir] + o);
  float h[4] = { h4[0], h4[1], h4[2], h4[3] };
  const unsigned short* xcp = s.xc[dir] + ((size_t)b * SEQ) * 1024 + d;
  const float* dtp = s.dt[dir] + ((size_t)b * SEQ) * 1024 + d;
  const unsigned short* zp  = s.xz[dir] + ((size_t)b * SEQ) * 2048 + 1024 + d;
  const float* dbp = s.dbl[dir] + ((size_t)b * SEQ) * 64;
  unsigned short* ysp = s.ys[dir] + ((size_t)b * SEQ) * 1024 + d;
  const int t0 = c * CL;
  for (int t = t0; t < t0 + CL; t++) {
    float dtv = dtp[(size_t)t * 1024];
    float xcv = bf2f(xcp[(size_t)t * 1024]);
    float dx = dtv * xcv;
    f32x4 Bv = *(const f32x4*)(dbp + (size_t)t * 64 + 32 + nq * 4);
    f32x4 Cv = *(const f32x4*)(dbp + (size_t)t * 64 + 48 + nq * 4);
    float y = 0.f;
    #pragma unroll
    for (int j = 0; j < 4; j++) {
      float e = __expf(dtv * A[j]);
      h[j] = e * h[j] + dx * Bv[j];
      y += h[j] * Cv[j];
    }
    // quad reduce over nq lanes (xor 1, 2 stay within the 4-lane group)
    y += __shfl_xor(y, 1);
    y += __shfl_xor(y, 2);
    if (nq == 0) {
      float z = bf2f(zp[(size_t)t * 2048]);
      float out = (y + xcv * Dv) * (z / (1.f + __expf(-z)));
      int tw = dir ? (SEQ - 1 - t) : t;
      ysp[(size_t)tw * 1024] = (unsigned short)f2bf(out);
    }
  }
}

extern "C" void kernel_launch(void* const* d_in, const int* in_sizes, int n_in,
                              void* d_out, int out_size, void* d_ws, size_t ws_size,
                              hipStream_t stream) {
  (void)in_sizes; (void)n_in; (void)out_size; (void)ws_size;
  const float* mel        = (const float*)d_in[0];
  const float* mel_w      = (const float*)d_in[1];
  const float* mel_b      = (const float*)d_in[2];
  const float* attn_in_b  = (const float*)d_in[4];
  const float* attn_out_b = (const float*)d_in[6];
  const float* ln1_g = (const float*)d_in[7];
  const float* ln1_b = (const float*)d_in[8];
  const float* ln2_g = (const float*)d_in[9];
  const float* ln2_b = (const float*)d_in[10];
  const float* bim_b = (const float*)d_in[30];
  const float* out_b = (const float*)d_in[32];

  char* wsb = (char*)d_ws;
  char* obb = (char*)d_out;

  // ---- bf16 weights in ws (byte offsets) ----
  unsigned short* w_attn_in  = (unsigned short*)(wsb + 0);          // 786432
  unsigned short* w_attn_out = (unsigned short*)(wsb + 1572864);    // 262144
  unsigned short* w_dir[2][4];
  for (int dir = 0; dir < 2; dir++) {
    size_t base = 2097152 + (size_t)dir * 3342336;
    w_dir[dir][0] = (unsigned short*)(wsb + base);                  // in_w
    w_dir[dir][1] = (unsigned short*)(wsb + base + 2097152);        // x_w
    w_dir[dir][2] = (unsigned short*)(wsb + base + 2228224);        // (spare)
    w_dir[dir][3] = (unsigned short*)(wsb + base + 2293760);        // out_w
  }
  unsigned short* w_bim = (unsigned short*)(wsb + 8781824);         // 524288
  unsigned short* w_out = (unsigned short*)(wsb + 9830400);         // 5120000

  // ---- bf16 activations in ws ----
  unsigned short* x0     = (unsigned short*)(wsb + 20971520);
  unsigned short* x1     = (unsigned short*)(wsb + 25165824);
  unsigned short* x1f    = (unsigned short*)(wsb + 29360128);
  unsigned short* attn_o = (unsigned short*)(wsb + 33554432);
  unsigned short* xc0    = (unsigned short*)(wsb + 37748736);  // 8.39MB
  unsigned short* ysb0   = (unsigned short*)(wsb + 46137344);  // 8.39MB
  unsigned short* mout   = (unsigned short*)(wsb + 62914560);  // 8.39MB
  unsigned short* minter = (unsigned short*)(wsb + 71303168);
  unsigned short* x2     = (unsigned short*)(wsb + 75497472);
  float*          dbl0   = (float*)(wsb + 79691776);           // 1.05MB
  unsigned short* melp   = (unsigned short*)(wsb + 80740352);  // 4096x128 bf16 = 1.05MB
  unsigned short* melwp  = (unsigned short*)(wsb + 81788928);  // 512x128 bf16 = 131072B

  // ---- d_out scratch (dead until final GEMM overwrites all; 163.84MB) ----
  unsigned short* qkv  = (unsigned short*)(obb + 0);           // 12.58MB
  unsigned short* xz0  = (unsigned short*)(obb + 12582912);    // 16.78MB
  unsigned short* xz1  = (unsigned short*)(obb + 29360128);    // 16.78MB
  unsigned short* xc1  = (unsigned short*)(obb + 46137344);    // 8.39MB
  unsigned short* ysb1 = (unsigned short*)(obb + 54525952);    // 8.39MB
  float* hend0 = (float*)(obb + 62914560);                     // 8.39MB
  float* hend1 = (float*)(obb + 71303168);
  float* apr0  = (float*)(obb + 79691776);
  float* apr1  = (float*)(obb + 88080384);
  float* h0s0  = (float*)(obb + 96468992);
  float* h0s1  = (float*)(obb + 104857600);
  float* dbl1  = (float*)(obb + 113246208);                    // 1.05MB
  float* dtf0  = (float*)(obb + 114294784);                    // 16.78MB
  float* dtf1  = (float*)(obb + 131072000);                    // 16.78MB -> ends 147.85MB
  float* ob    = (float*)d_out;

  dim3 blk(256);

  // 0. convert weights to bf16; pad-convert mel + mel_w to K=128 bf16
  {
    CvtArgs a;
    const float* srcs[12] = { (const float*)d_in[3], (const float*)d_in[5],
      (const float*)d_in[11], (const float*)d_in[14], (const float*)d_in[15], (const float*)d_in[19],
      (const float*)d_in[20], (const float*)d_in[23], (const float*)d_in[24], (const float*)d_in[28],
      (const float*)d_in[29], (const float*)d_in[31] };
    unsigned short* dsts[12] = { w_attn_in, w_attn_out,
      w_dir[0][0], w_dir[0][1], w_dir[0][2], w_dir[0][3],
      w_dir[1][0], w_dir[1][1], w_dir[1][2], w_dir[1][3],
      w_bim, w_out };
    int ns[12] = { 786432, 262144, 1048576, 65536, 32768, 524288,
                   1048576, 65536, 32768, 524288, 524288, 5120000 };
    for (int i = 0; i < 12; i++) { a.s[i] = srcs[i]; a.d[i] = dsts[i]; a.n[i] = ns[i]; }
    cvt_many<<<dim3(2500, 12), blk, 0, stream>>>(a);
    cvt_pad<<<dim3(256, 2), blk, 0, stream>>>(mel, melp, 4096, mel_w, melwp, 512);
  }

  // 1. x0 = melp @ melwp.T + mel_b  (bf16 path, K=128 zero-padded)
  gemm_bf16<1, 1><<<dim3(4 * 32), blk, 0, stream>>>(melp, melwp, x0, mel_b,
      4096, 512, 128, 128, 128, 512, 4, nullptr, nullptr, nullptr);
  // 2. qkv = x0 @ attn_in_w.T + b
  gemm_bf16<1, 1><<<dim3(12 * 32), blk, 0, stream>>>(x0, w_attn_in, qkv, attn_in_b,
      4096, 1536, 512, 512, 512, 1536, 12, nullptr, nullptr, nullptr);
  // 3. attention
  attn_kernel<<<4096, blk, 0, stream>>>(qkv, attn_o);
  // 4. attnproj -> qkv slot
  gemm_bf16<1, 1><<<dim3(4 * 32), blk, 0, stream>>>(attn_o, w_attn_out, qkv, attn_out_b,
      4096, 512, 512, 512, 512, 512, 4, nullptr, nullptr, nullptr);
  // 5. x1 = LN(x0 + attnproj); x1f = flip(x1) fused
  ln_res_kernel<1><<<1024, blk, 0, stream>>>(x0, qkv, ln1_g, ln1_b, x1, x1f);

  // ---- dual-direction mamba pipeline (blockIdx.y = dir) ----
  ScanArgs sa;
  ConvArgs ca;
  for (int dir = 0; dir < 2; dir++) {
    int base = 11 + dir * 9;
    ca.xz[dir] = dir ? xz1 : xz0;
    ca.w[dir]  = (const float*)d_in[base + 1];
    ca.cb[dir] = (const float*)d_in[base + 2];
    ca.xc[dir] = dir ? xc1 : xc0;
    sa.xc[dir]    = dir ? xc1 : xc0;
    sa.dbl[dir]   = dir ? dbl1 : dbl0;
    sa.A_log[dir] = (const float*)d_in[base + 6];
    sa.dt[dir]    = dir ? dtf1 : dtf0;
    sa.Dp[dir]    = (const float*)d_in[base + 7];
    sa.xz[dir]    = dir ? xz1 : xz0;
    sa.hend[dir]  = dir ? hend1 : hend0;
    sa.apr[dir]   = dir ? apr1 : apr0;
    sa.h0[dir]    = dir ? h0s1 : h0s0;
    sa.ys[dir]    = dir ? ysb1 : ysb0;
  }
  // xz = xin @ in_w.T  (dual)
  gemm_bf16<0, 1><<<dim3(16 * 32, 2), blk, 0, stream>>>(x1, w_dir[0][0], xz0, nullptr,
      4096, 2048, 512, 512, 512, 2048, 16, x1f, w_dir[1][0], xz1);
  // conv + silu (dual)
  conv_silu_kernel<<<dim3(2048, 2), blk, 0, stream>>>(ca);
  // dbl = xc @ x_w.T (dual, f32 out for scan numerics)
  gemm_bf16<0, 0><<<dim3(1 * 32, 2), blk, 0, stream>>>(xc0, w_dir[0][1], dbl0, nullptr,
      4096, 64, 1024, 1024, 1024, 64, 1, xc1, w_dir[1][1], dbl1);
  // dt = softplus(dbl[:, :32] @ dt_w.T + dt_b)  (dedicated f32 matvec, dual)
  dt_kernel<<<dim3(256, 2), dim3(512), 0, stream>>>(
      dbl0, (const float*)d_in[15], (const float*)d_in[16], dtf0,
      dbl1, (const float*)d_in[24], (const float*)d_in[25], dtf1);
  // selective scan (dual; 4 lanes per (b,c,d); gate + output-flip fused into p3)
  scan_p1<<<dim3(2048, 2), blk, 0, stream>>>(sa);
  scan_p2<<<dim3(128, 2), blk, 0, stream>>>(sa);
  scan_p3<<<dim3(2048, 2), blk, 0, stream>>>(sa);
  // mamba out proj (dual) -> mout cols [dir*512, +512)
  gemm_bf16<0, 1><<<dim3(4 * 32, 2), blk, 0, stream>>>(ysb0, w_dir[0][3], mout, nullptr,
      4096, 512, 1024, 1024, 1024, 1024, 4, ysb1, w_dir[1][3], mout + 512);

  // m = mout @ bim_w.T + bim_b
  gemm_bf16<1, 1><<<dim3(4 * 32), blk, 0, stream>>>(mout, w_bim, minter, bim_b,
      4096, 512, 1024, 1024, 1024, 512, 4, nullptr, nullptr, nullptr);
  // x2 = LN(x1 + m)
  ln_res_kernel<0><<<1024, blk, 0, stream>>>(x1, minter, ln2_g, ln2_b, x2, nullptr);
  // logits = x2 @ out_w.T + out_b  (overwrites all of d_out; nontemporal f32 stores)
  gemm_bf16<1, 0><<<dim3(79 * 32), blk, 0, stream>>>(x2, w_out, ob, out_b,
      4096, 10000, 512, 512, 512, 10000, 79, nullptr, nullptr, nullptr);
}